// Round 16
// baseline (125.518 us; speedup 1.0000x reference)
//
#include <hip/hip_runtime.h>
#include <math.h>

typedef _Float16 f16;
typedef _Float16 f16x2 __attribute__((ext_vector_type(2)));
typedef _Float16 f16x4 __attribute__((ext_vector_type(4)));
typedef _Float16 f16x8 __attribute__((ext_vector_type(8)));
typedef float    f32x4 __attribute__((ext_vector_type(4)));

constexpr int DIM   = 1024;
constexpr int HEADS = 16;
constexpr int HD    = 64;
constexpr int BATCH = 2;
constexpr int SEQ   = 2048;
constexpr int MTOT  = BATCH * SEQ;   // 4096
constexpr int NT2   = SEQ / 128;     // 16 staged KV tiles of 128

// exp(q.k/64) == exp2((q * log2e/64) . k): fold into Q projection scale.
#define QSCALE (1.4426950408889634f / 64.0f)

#define MFMA16(a, b, c) __builtin_amdgcn_mfma_f32_16x16x32_f16((a), (b), (c), 0, 0, 0)

__device__ __forceinline__ void glds16(const void* g, void* l) {
    __builtin_amdgcn_global_load_lds(
        (const __attribute__((address_space(1))) void*)g,
        (__attribute__((address_space(3))) void*)l, 16, 0, 0);
}

__device__ __forceinline__ float exp2_hw(float x) {
    float r;
    asm("v_exp_f32 %0, %1" : "=v"(r) : "v"(x));   // D = 2^S0
    return r;
}

__device__ __forceinline__ f16x2 pk_f16(float a, float b) {
    return __builtin_bit_cast(f16x2, __builtin_amdgcn_cvt_pkrtz(a, b));
}

// ---------------------------------------------------------------------------
// Pre-split pass: fp32 -> f16 hi planes, GEMM fragment-read swizzle baked:
// within each 32-half k-tile, 8-half slot ^= ((row>>1)&3).
// ---------------------------------------------------------------------------
__global__ __launch_bounds__(256) void presplit_kernel(
    const float* __restrict__ x,  const float* __restrict__ Wq,
    const float* __restrict__ Wk, const float* __restrict__ Wv,
    const float* __restrict__ Wo,
    f16* __restrict__ Xh,  f16* __restrict__ WqH, f16* __restrict__ WkH,
    f16* __restrict__ WvH, f16* __restrict__ WoH)
{
    const int bid = blockIdx.x;
    const float* src; f16* dh; int row;
    if (bid < 4096)      { src = x;  dh = Xh;  row = bid; }
    else if (bid < 5120) { src = Wq; dh = WqH; row = bid - 4096; }
    else if (bid < 6144) { src = Wk; dh = WkH; row = bid - 5120; }
    else if (bid < 7168) { src = Wv; dh = WvH; row = bid - 6144; }
    else                 { src = Wo; dh = WoH; row = bid - 7168; }

    const int k = threadIdx.x * 4;
    const float4 v = *reinterpret_cast<const float4*>(&src[(size_t)row * DIM + k]);
    const int s = (row >> 1) & 3;
    const size_t o = (size_t)row * DIM + (k & ~31) + ((k & 31) ^ (s << 3));
    f16x4 h4;
    h4[0] = (f16)v.x; h4[1] = (f16)v.y; h4[2] = (f16)v.z; h4[3] = (f16)v.w;
    *reinterpret_cast<f16x4*>(&dh[o]) = h4;
}

// ---------------------------------------------------------------------------
// 1-term plane GEMM, BK=32, T4 counted-vmcnt dbuf (R15 proven):
// per k-step {GSTAGE(next); vmcnt(4); s_barrier; ds_read+MFMA; s_barrier}.
// BM=BN=128, 4 waves, LDS 2x16 KB dbuf.
// MODE 0: C=(acc+bias)*scale -> fp32.   MODE 3: F=(acc+bias)*scale -> f16.
// MODE 1: K hi plane [bh][kv][ d ^ ((kv&7)<<3) ]  (transposed compute)
// MODE 2: V hi plane [bh][d][ kv ^ ((d&7)<<3) ]
// ---------------------------------------------------------------------------
template <int MODE>
__device__ __forceinline__ void gemm_plane_body(
    const f16* __restrict__ AhG, const f16* __restrict__ BhG,
    const float* __restrict__ bias, float* __restrict__ C,
    f16* __restrict__ F, float scale, f16* __restrict__ smem)
{
    const int tid = threadIdx.x;
    const int l   = tid & 63;
    const int w   = tid >> 6;
    const int wm  = (w >> 1) * 64;
    const int wn  = (w & 1) * 64;
    const int m0  = blockIdx.y * 128;
    const int n0  = blockIdx.x * 128;
    const int fr  = l & 15;
    const int fk  = (l >> 4) * 8;
    const int rg  = (l >> 4) * 4;
    const int fko = fk ^ (((fr >> 1) & 3) << 3);   // swizzled k-slot

    f32x4 acc[4][4] = {};

#define GSTAGE(B, K0) do {                                                  \
        _Pragma("unroll")                                                   \
        for (int j = 0; j < 4; ++j) {                                       \
            const int c = w * 4 + j;             /* 0..15 */                \
            const int p = c >> 3;                /* 0 = A, 1 = B */         \
            const f16* P = (p == 0) ? AhG : BhG;                            \
            const int r0 = (p == 0) ? m0 : n0;                              \
            const int row = r0 + (c & 7) * 16 + (l >> 2);                   \
            glds16(P + (size_t)row * DIM + (K0) + (l & 3) * 8,              \
                   smem + (B) * 8192 + c * 512);                            \
        }                                                                   \
    } while (0)

    GSTAGE(0, 0);
    int cur = 0;

    for (int k0 = 0; k0 < DIM; k0 += 32) {
        if (k0 + 32 < DIM) {
            GSTAGE(cur ^ 1, k0 + 32);   // 4 loads/wave for next tile in flight
            asm volatile("s_waitcnt vmcnt(4)\ns_barrier" ::: "memory");
        } else {
            asm volatile("s_waitcnt vmcnt(0)\ns_barrier" ::: "memory");
        }

        const f16* Ah = smem + cur * 8192;
        const f16* Bh = Ah + 4096;

        f16x8 ah[4], bh[4];
        #pragma unroll
        for (int m = 0; m < 4; ++m)
            ah[m] = *reinterpret_cast<const f16x8*>(&Ah[(wm + m * 16 + fr) * 32 + fko]);
        #pragma unroll
        for (int n = 0; n < 4; ++n)
            bh[n] = *reinterpret_cast<const f16x8*>(&Bh[(wn + n * 16 + fr) * 32 + fko]);
        #pragma unroll
        for (int n = 0; n < 4; ++n)
            #pragma unroll
            for (int m = 0; m < 4; ++m) {
                if (MODE == 1)   // transposed: D[d][token]
                    acc[m][n] = MFMA16(bh[n], ah[m], acc[m][n]);
                else
                    acc[m][n] = MFMA16(ah[m], bh[n], acc[m][n]);
            }
        asm volatile("s_barrier" ::: "memory");
        cur ^= 1;
    }
#undef GSTAGE

    if (MODE == 0 || MODE == 3) {
        #pragma unroll
        for (int n = 0; n < 4; ++n) {
            const int col  = n0 + wn + n * 16 + fr;
            const float bb = bias[col];
            #pragma unroll
            for (int m = 0; m < 4; ++m) {
                #pragma unroll
                for (int r = 0; r < 4; ++r) {
                    const int row = m0 + wm + m * 16 + rg + r;
                    const float v = (acc[m][n][r] + bb) * scale;
                    if (MODE == 0) C[(size_t)row * DIM + col] = v;
                    else           F[(size_t)row * DIM + col] = (f16)v;
                }
            }
        }
    } else if (MODE == 1) {
        constexpr int RS = 72;
        const int batch = m0 >> 11;
        const int kvg0  = m0 & 2047;
        for (int s = 0; s < 2; ++s) {
            __syncthreads();
            if ((w & 1) == s) {
                #pragma unroll
                for (int n = 0; n < 4; ++n) {
                    #pragma unroll
                    for (int m = 0; m < 4; ++m) {
                        const int kvrow = wm + m * 16 + fr;
                        const int dd    = n * 16 + rg;
                        f16x4 h4;
                        #pragma unroll
                        for (int r = 0; r < 4; ++r)
                            h4[r] = (f16)(acc[m][n][r] + bias[n0 + wn + dd + r]);
                        const int o = kvrow * RS + (dd ^ ((kvrow & 7) << 3));
                        *reinterpret_cast<f16x4*>(&smem[o]) = h4;
                    }
                }
            }
            __syncthreads();
            const size_t bh_ = (size_t)batch * HEADS + (n0 >> 6) + s;
            const int row = tid >> 1, c0 = (tid & 1) * 32;
            #pragma unroll
            for (int j = 0; j < 4; ++j) {
                const int so = row * RS + c0 + j * 8;
                const size_t go = bh_ * 131072 + (size_t)(kvg0 + row) * 64 + c0 + j * 8;
                *reinterpret_cast<f16x8*>(&F[go]) =
                    *reinterpret_cast<const f16x8*>(&smem[so]);
            }
        }
    } else {
        constexpr int RS = 136;
        const int batch = m0 >> 11;
        const int kvg0  = m0 & 2047;
        for (int s = 0; s < 2; ++s) {
            __syncthreads();
            if ((w & 1) == s) {
                #pragma unroll
                for (int n = 0; n < 4; ++n) {
                    const int d    = n * 16 + fr;
                    const float bb = bias[n0 + wn + d];
                    #pragma unroll
                    for (int m = 0; m < 4; ++m) {
                        const int kvl = wm + m * 16 + rg;
                        f16x4 h4;
                        h4[0] = (f16)(acc[m][n][0] + bb);
                        h4[1] = (f16)(acc[m][n][1] + bb);
                        h4[2] = (f16)(acc[m][n][2] + bb);
                        h4[3] = (f16)(acc[m][n][3] + bb);
                        const int o = d * RS + (kvl ^ ((d & 7) << 3));
                        *reinterpret_cast<f16x4*>(&smem[o]) = h4;
                    }
                }
            }
            __syncthreads();
            const size_t bh_ = (size_t)batch * HEADS + (n0 >> 6) + s;
            const int row = tid >> 2, c0 = (tid & 3) * 32;
            #pragma unroll
            for (int j = 0; j < 4; ++j) {
                const int so = row * RS + c0 + j * 8;
                const size_t go = bh_ * 131072 + (size_t)row * 2048 + kvg0 + c0 + j * 8;
                *reinterpret_cast<f16x8*>(&F[go]) =
                    *reinterpret_cast<const f16x8*>(&smem[so]);
            }
        }
    }
}

__global__ __launch_bounds__(256) void qkv_kernel(
    const f16* __restrict__ XhG,
    const f16* __restrict__ WqH, const float* __restrict__ bq,
    const f16* __restrict__ WkH, const float* __restrict__ bk,
    const f16* __restrict__ WvH, const float* __restrict__ bv,
    f16* __restrict__ QhG, f16* __restrict__ KhG, f16* __restrict__ VhG)
{
    __shared__ __align__(16) f16 smem[18432];  // 36 KB (dbuf 32 KB; K-repack 18 KB)
    if (blockIdx.z == 0)
        gemm_plane_body<3>(XhG, WqH, bq, nullptr, QhG, QSCALE, smem);
    else if (blockIdx.z == 1)
        gemm_plane_body<1>(XhG, WkH, bk, nullptr, KhG, 1.0f, smem);
    else
        gemm_plane_body<2>(XhG, WvH, bv, nullptr, VhG, 1.0f, smem);
}

__global__ __launch_bounds__(256) void oproj_kernel(
    const f16* __restrict__ OhG, const f16* __restrict__ WoH,
    const float* __restrict__ bo, float* __restrict__ out)
{
    __shared__ __align__(16) f16 smem[16384];  // 32 KB dbuf
    gemm_plane_body<0>(OhG, WoH, bo, out, nullptr, 1.0f, smem);
}

// ---------------------------------------------------------------------------
// Flash attention v10: QBLK=64 per wave (4 q-streams x 16), 256 q-rows/block,
// 256 blocks (1/CU, 1 wave/SIMD -> VGPR headroom to 512). K/V LDS reads
// amortized over 4 q-streams (-29% LDS/q); staging DMA per CU halved.
// Per-q math identical to R12 (bit-identical output). KVBLK=128 dbuf,
// pure-f16 MFMA, exp2 scores, lsum via ones-MFMA, XCD swizzle, setprio.
// ---------------------------------------------------------------------------
__global__ __launch_bounds__(256, 1) void attn_kernel(
    const f16* __restrict__ QhG, const f16* __restrict__ KhG,
    const f16* __restrict__ VhG, f16* __restrict__ OhG)
{
    __shared__ __align__(16) f16 lds[2][2][8192];   // 64 KB: Kh, Vh dbuf (128 kv)
    __shared__ __align__(16) f16 PL[4][4][1024];    // 32 KB per-wave per-qs P^T

    const int tid = threadIdx.x;
    const int l   = tid & 63;
    const int w   = tid >> 6;
    const int fr  = l & 15;
    const int g   = l >> 4;
    const int fk  = g * 8;
    const int rg  = g * 4;
    const int swz = (fr & 7) << 3;

    // 256 blocks, 32-block chunks per XCD (4 bh -> 2 MB K+V per XCD L2)
    const int lin  = blockIdx.x + 8 * (blockIdx.y + 16 * blockIdx.z);
    const int sid  = (lin & 7) * 32 + (lin >> 3);
    const int qblk = sid & 7;
    const int head = (sid >> 3) & 15;
    const int batch = sid >> 7;

    const int q0 = qblk * 256;
    const size_t rowbase = (size_t)batch * SEQ;
    const int hcol = head * HD;
    const size_t bhbase = ((size_t)batch * HEADS + head) * (size_t)(SEQ * HD);

    size_t kA[4], vA[4];
    #pragma unroll
    for (int c = 0; c < 4; ++c) {
        const int h0 = (w * 4 + c) * 512 + l * 8;
        kA[c] = bhbase + (size_t)h0;                               // + t*8192
        vA[c] = bhbase + (size_t)(h0 >> 7) * 2048 + (h0 & 127);    // + t*128
    }

#define STAGE(B, T) do {                                                    \
        const size_t _ko = (size_t)(T) * 8192;                              \
        const size_t _vo = (size_t)(T) * 128;                               \
        _Pragma("unroll")                                                   \
        for (int c = 0; c < 4; ++c) {                                       \
            const int lo_ = (w * 4 + c) * 512;                              \
            glds16(KhG + kA[c] + _ko, &lds[B][0][lo_]);                     \
            glds16(VhG + vA[c] + _vo, &lds[B][1][lo_]);                     \
        }                                                                   \
    } while (0)

    STAGE(0, 0);

    // Q fragments: 4 q-streams x 16 rows, f16, pre-scaled by log2e/64
    f16x8 qh[4][2];
    #pragma unroll
    for (int qs = 0; qs < 4; ++qs) {
        const f16* qp = &QhG[(rowbase + q0 + w * 64 + qs * 16 + fr) * DIM + hcol];
        qh[qs][0] = *reinterpret_cast<const f16x8*>(&qp[fk]);
        qh[qs][1] = *reinterpret_cast<const f16x8*>(&qp[32 + fk]);
    }

    f16x8 onesv;
    #pragma unroll
    for (int i = 0; i < 8; ++i) onesv[i] = (f16)1.0f;

    f32x4 ls[4] = {};
    f32x4 oa[4][4] = {};   // [db][qs]

    int cur = 0;
    for (int t = 0; t < NT2; ++t) {
        asm volatile("s_waitcnt vmcnt(0) lgkmcnt(0)\ns_barrier" ::: "memory");
        if (t + 1 < NT2) STAGE(cur ^ 1, t + 1);

        #pragma unroll
        for (int hh = 0; hh < 2; ++hh) {     // two 64-kv halves
            const f16* Kh = &lds[cur][0][hh * 4096];
            const f16* Vh = &lds[cur][1][hh * 64];

            // ---- S'^T = K Q'^T : K fragments shared across 4 q-streams ----
            f32x4 sa[4][4] = {};
            __builtin_amdgcn_s_setprio(1);
            #pragma unroll
            for (int kvb = 0; kvb < 4; ++kvb) {
                #pragma unroll
                for (int ks = 0; ks < 2; ++ks) {
                    const int o = ((kvb * 16 + fr) * 64 + ks * 32 + fk) ^ swz;
                    const f16x8 kh = *reinterpret_cast<const f16x8*>(&Kh[o]);
                    #pragma unroll
                    for (int qs = 0; qs < 4; ++qs)
                        sa[kvb][qs] = MFMA16(kh, qh[qs][ks], sa[kvb][qs]);
                }
            }
            __builtin_amdgcn_s_setprio(0);

            // ---- P = 2^s per q-stream, pack, stash in per-wave LDS ----
            f16x8 pf[4][2];
            #pragma unroll
            for (int qs = 0; qs < 4; ++qs) {
                f16* Wh = &PL[w][qs][0];
                #pragma unroll
                for (int kvb = 0; kvb < 4; ++kvb) {
                    const f16x2 p01 = pk_f16(exp2_hw(sa[kvb][qs][0]),
                                             exp2_hw(sa[kvb][qs][1]));
                    const f16x2 p23 = pk_f16(exp2_hw(sa[kvb][qs][2]),
                                             exp2_hw(sa[kvb][qs][3]));
                    f16x4 h4;
                    h4[0] = p01[0]; h4[1] = p01[1]; h4[2] = p23[0]; h4[3] = p23[1];
                    const int po = (fr * 64 + kvb * 16 + rg) ^ swz;
                    *reinterpret_cast<f16x4*>(&Wh[po]) = h4;
                }
                #pragma unroll
                for (int ks = 0; ks < 2; ++ks) {
                    const int ro = (fr * 64 + ks * 32 + fk) ^ swz;
                    pf[qs][ks] = *reinterpret_cast<const f16x8*>(&Wh[ro]);
                }
            }

            // ---- lsum += colsum(P); O^T += V^T P^T (V shared across qs) ----
            __builtin_amdgcn_s_setprio(1);
            #pragma unroll
            for (int qs = 0; qs < 4; ++qs)
                #pragma unroll
                for (int ks = 0; ks < 2; ++ks)
                    ls[qs] = MFMA16(onesv, pf[qs][ks], ls[qs]);
            #pragma unroll
            for (int db = 0; db < 4; ++db) {
                #pragma unroll
                for (int ks = 0; ks < 2; ++ks) {
                    const int vo = (db * 16 + fr) * 128 + ((ks * 32 + fk) ^ swz);
                    const f16x8 vh = *reinterpret_cast<const f16x8*>(&Vh[vo]);
                    #pragma unroll
                    for (int qs = 0; qs < 4; ++qs)
                        oa[db][qs] = MFMA16(vh, pf[qs][ks], oa[db][qs]);
                }
            }
            __builtin_amdgcn_s_setprio(0);
        }
        cur ^= 1;
    }
#undef STAGE

    // ---- epilogue: O hi plane (swizzled for oproj staging) ----
    #pragma unroll
    for (int qs = 0; qs < 4; ++qs) {
        const float inv = 1.0f / ls[qs][0];
        const size_t row = rowbase + q0 + w * 64 + qs * 16 + fr;
        const int s = ((int)row >> 1) & 3;
        #pragma unroll
        for (int db = 0; db < 4; ++db) {
            f16x4 h4;
            #pragma unroll
            for (int j = 0; j < 4; ++j) h4[j] = (f16)(oa[db][qs][j] * inv);
            const int kg = hcol + db * 16 + rg;
            const size_t o = row * DIM + (kg & ~31) + ((kg & 31) ^ (s << 3));
            *reinterpret_cast<f16x4*>(&OhG[o]) = h4;
        }
    }
}

extern "C" void kernel_launch(void* const* d_in, const int* in_sizes, int n_in,
                              void* d_out, int out_size, void* d_ws, size_t ws_size,
                              hipStream_t stream)
{
    const float* x  = (const float*)d_in[0];
    const float* Wq = (const float*)d_in[1];
    const float* bq = (const float*)d_in[2];
    const float* Wk = (const float*)d_in[3];
    const float* bk = (const float*)d_in[4];
    const float* Wv = (const float*)d_in[5];
    const float* bv = (const float*)d_in[6];
    const float* Wo = (const float*)d_in[7];
    const float* bo = (const float*)d_in[8];
    float* out = (float*)d_out;

    const size_t PS = (size_t)MTOT * DIM;   // 4,194,304 elements
    f16* QhG = (f16*)d_ws;                  // 8 MB each
    f16* KhG = QhG + PS;
    f16* VhG = KhG + PS;
    f16* XhG = VhG + PS;                    // reused as Oh after qkv
    f16* WqH = XhG + PS;                    // 2 MB each below
    f16* WkH = WqH + (size_t)DIM * DIM;
    f16* WvH = WkH + (size_t)DIM * DIM;
    f16* WoH = WvH + (size_t)DIM * DIM;
    f16* OhG = XhG;                         // alias: x consumed before attn

    presplit_kernel<<<8192, 256, 0, stream>>>(x, Wq, Wk, Wv, Wo,
                                              XhG, WqH, WkH, WvH, WoH);

    dim3 gqkv(DIM / 128, MTOT / 128, 3);
    qkv_kernel<<<gqkv, 256, 0, stream>>>(XhG, WqH, bq, WkH, bk, WvH, bv,
                                         QhG, KhG, VhG);

    dim3 gattn(SEQ / 256, HEADS, BATCH);
    attn_kernel<<<gattn, 256, 0, stream>>>(QhG, KhG, VhG, OhG);

    dim3 gout(DIM / 128, MTOT / 128);
    oproj_kernel<<<gout, 256, 0, stream>>>(OhG, WoH, bo, out);
}

// Round 17
// 112.441 us; speedup vs baseline: 1.1163x; 1.1163x over previous
//
#include <hip/hip_runtime.h>
#include <math.h>

typedef _Float16 f16;
typedef _Float16 f16x2 __attribute__((ext_vector_type(2)));
typedef _Float16 f16x4 __attribute__((ext_vector_type(4)));
typedef _Float16 f16x8 __attribute__((ext_vector_type(8)));
typedef float    f32x4 __attribute__((ext_vector_type(4)));

constexpr int DIM   = 1024;
constexpr int HEADS = 16;
constexpr int HD    = 64;
constexpr int BATCH = 2;
constexpr int SEQ   = 2048;
constexpr int MTOT  = BATCH * SEQ;   // 4096
constexpr int NT2   = SEQ / 128;     // 16 staged KV tiles of 128

// exp(q.k/64) == exp2((q * log2e/64) . k): fold into Q projection scale.
#define QSCALE (1.4426950408889634f / 64.0f)

#define MFMA16(a, b, c) __builtin_amdgcn_mfma_f32_16x16x32_f16((a), (b), (c), 0, 0, 0)

__device__ __forceinline__ void glds16(const void* g, void* l) {
    __builtin_amdgcn_global_load_lds(
        (const __attribute__((address_space(1))) void*)g,
        (__attribute__((address_space(3))) void*)l, 16, 0, 0);
}

__device__ __forceinline__ float exp2_hw(float x) {
    float r;
    asm("v_exp_f32 %0, %1" : "=v"(r) : "v"(x));   // D = 2^S0
    return r;
}

__device__ __forceinline__ f16x2 pk_f16(float a, float b) {
    return __builtin_bit_cast(f16x2, __builtin_amdgcn_cvt_pkrtz(a, b));
}

// ---------------------------------------------------------------------------
// Pre-split pass: fp32 -> f16 hi planes, GEMM fragment-read swizzle baked:
// within each 32-half k-tile, 8-half slot ^= ((row>>1)&3).
// ---------------------------------------------------------------------------
__global__ __launch_bounds__(256) void presplit_kernel(
    const float* __restrict__ x,  const float* __restrict__ Wq,
    const float* __restrict__ Wk, const float* __restrict__ Wv,
    const float* __restrict__ Wo,
    f16* __restrict__ Xh,  f16* __restrict__ WqH, f16* __restrict__ WkH,
    f16* __restrict__ WvH, f16* __restrict__ WoH)
{
    const int bid = blockIdx.x;
    const float* src; f16* dh; int row;
    if (bid < 4096)      { src = x;  dh = Xh;  row = bid; }
    else if (bid < 5120) { src = Wq; dh = WqH; row = bid - 4096; }
    else if (bid < 6144) { src = Wk; dh = WkH; row = bid - 5120; }
    else if (bid < 7168) { src = Wv; dh = WvH; row = bid - 6144; }
    else                 { src = Wo; dh = WoH; row = bid - 7168; }

    const int k = threadIdx.x * 4;
    const float4 v = *reinterpret_cast<const float4*>(&src[(size_t)row * DIM + k]);
    const int s = (row >> 1) & 3;
    const size_t o = (size_t)row * DIM + (k & ~31) + ((k & 31) ^ (s << 3));
    f16x4 h4;
    h4[0] = (f16)v.x; h4[1] = (f16)v.y; h4[2] = (f16)v.z; h4[3] = (f16)v.w;
    *reinterpret_cast<f16x4*>(&dh[o]) = h4;
}

// ---------------------------------------------------------------------------
// 1-term plane GEMM, BK=32, T4 3-buffer ring with 2-deep prefetch:
// per k-step {GSTAGE(t+2 -> buf2); vmcnt(8); s_barrier; ds_read+MFMA(buf0);
// s_barrier; rotate}. Stage-t loads issued 2 steps (~400cy) before use ->
// L2 latency fully hidden (R15's 1-deep vmcnt(4) only covered ~half).
// BM=BN=128, 4 waves, LDS 3x16 KB ring.
// MODE 0: C=(acc+bias)*scale -> fp32.   MODE 3: F=(acc+bias)*scale -> f16.
// MODE 1: K hi plane [bh][kv][ d ^ ((kv&7)<<3) ]  (transposed compute)
// MODE 2: V hi plane [bh][d][ kv ^ ((d&7)<<3) ]
// ---------------------------------------------------------------------------
template <int MODE>
__device__ __forceinline__ void gemm_plane_body(
    const f16* __restrict__ AhG, const f16* __restrict__ BhG,
    const float* __restrict__ bias, float* __restrict__ C,
    f16* __restrict__ F, float scale, f16* __restrict__ smem)
{
    const int tid = threadIdx.x;
    const int l   = tid & 63;
    const int w   = tid >> 6;
    const int wm  = (w >> 1) * 64;
    const int wn  = (w & 1) * 64;
    const int m0  = blockIdx.y * 128;
    const int n0  = blockIdx.x * 128;
    const int fr  = l & 15;
    const int fk  = (l >> 4) * 8;
    const int rg  = (l >> 4) * 4;
    const int fko = fk ^ (((fr >> 1) & 3) << 3);   // swizzled k-slot

    f32x4 acc[4][4] = {};

#define GSTAGE(B, K0) do {                                                  \
        _Pragma("unroll")                                                   \
        for (int j = 0; j < 4; ++j) {                                       \
            const int c = w * 4 + j;             /* 0..15 */                \
            const int p = c >> 3;                /* 0 = A, 1 = B */         \
            const f16* P = (p == 0) ? AhG : BhG;                            \
            const int r0 = (p == 0) ? m0 : n0;                              \
            const int row = r0 + (c & 7) * 16 + (l >> 2);                   \
            glds16(P + (size_t)row * DIM + (K0) + (l & 3) * 8,              \
                   smem + (B) * 8192 + c * 512);                            \
        }                                                                   \
    } while (0)

    GSTAGE(0, 0);
    GSTAGE(1, 32);
    int b0 = 0, b1 = 1, b2 = 2;   // compute, in-flight, stage-target

    for (int k0 = 0; k0 < DIM; k0 += 32) {
        if (k0 + 64 < DIM) {
            GSTAGE(b2, k0 + 64);   // 2 tiles (8 loads/wave) stay in flight
            asm volatile("s_waitcnt vmcnt(8)\ns_barrier" ::: "memory");
        } else if (k0 + 32 < DIM) {
            asm volatile("s_waitcnt vmcnt(4)\ns_barrier" ::: "memory");
        } else {
            asm volatile("s_waitcnt vmcnt(0)\ns_barrier" ::: "memory");
        }

        const f16* Ah = smem + b0 * 8192;
        const f16* Bh = Ah + 4096;

        f16x8 ah[4], bh[4];
        #pragma unroll
        for (int m = 0; m < 4; ++m)
            ah[m] = *reinterpret_cast<const f16x8*>(&Ah[(wm + m * 16 + fr) * 32 + fko]);
        #pragma unroll
        for (int n = 0; n < 4; ++n)
            bh[n] = *reinterpret_cast<const f16x8*>(&Bh[(wn + n * 16 + fr) * 32 + fko]);
        #pragma unroll
        for (int n = 0; n < 4; ++n)
            #pragma unroll
            for (int m = 0; m < 4; ++m) {
                if (MODE == 1)   // transposed: D[d][token]
                    acc[m][n] = MFMA16(bh[n], ah[m], acc[m][n]);
                else
                    acc[m][n] = MFMA16(ah[m], bh[n], acc[m][n]);
            }
        // all waves done reading b0 before any wave overwrites it (as new b2)
        asm volatile("s_barrier" ::: "memory");
        const int tmp = b0; b0 = b1; b1 = b2; b2 = tmp;
    }
#undef GSTAGE

    if (MODE == 0 || MODE == 3) {
        #pragma unroll
        for (int n = 0; n < 4; ++n) {
            const int col  = n0 + wn + n * 16 + fr;
            const float bb = bias[col];
            #pragma unroll
            for (int m = 0; m < 4; ++m) {
                #pragma unroll
                for (int r = 0; r < 4; ++r) {
                    const int row = m0 + wm + m * 16 + rg + r;
                    const float v = (acc[m][n][r] + bb) * scale;
                    if (MODE == 0) C[(size_t)row * DIM + col] = v;
                    else           F[(size_t)row * DIM + col] = (f16)v;
                }
            }
        }
    } else if (MODE == 1) {
        constexpr int RS = 72;
        const int batch = m0 >> 11;
        const int kvg0  = m0 & 2047;
        for (int s = 0; s < 2; ++s) {
            __syncthreads();
            if ((w & 1) == s) {
                #pragma unroll
                for (int n = 0; n < 4; ++n) {
                    #pragma unroll
                    for (int m = 0; m < 4; ++m) {
                        const int kvrow = wm + m * 16 + fr;
                        const int dd    = n * 16 + rg;
                        f16x4 h4;
                        #pragma unroll
                        for (int r = 0; r < 4; ++r)
                            h4[r] = (f16)(acc[m][n][r] + bias[n0 + wn + dd + r]);
                        const int o = kvrow * RS + (dd ^ ((kvrow & 7) << 3));
                        *reinterpret_cast<f16x4*>(&smem[o]) = h4;
                    }
                }
            }
            __syncthreads();
            const size_t bh_ = (size_t)batch * HEADS + (n0 >> 6) + s;
            const int row = tid >> 1, c0 = (tid & 1) * 32;
            #pragma unroll
            for (int j = 0; j < 4; ++j) {
                const int so = row * RS + c0 + j * 8;
                const size_t go = bh_ * 131072 + (size_t)(kvg0 + row) * 64 + c0 + j * 8;
                *reinterpret_cast<f16x8*>(&F[go]) =
                    *reinterpret_cast<const f16x8*>(&smem[so]);
            }
        }
    } else {
        constexpr int RS = 136;
        const int batch = m0 >> 11;
        const int kvg0  = m0 & 2047;
        for (int s = 0; s < 2; ++s) {
            __syncthreads();
            if ((w & 1) == s) {
                #pragma unroll
                for (int n = 0; n < 4; ++n) {
                    const int d    = n * 16 + fr;
                    const float bb = bias[n0 + wn + d];
                    #pragma unroll
                    for (int m = 0; m < 4; ++m) {
                        const int kvl = wm + m * 16 + rg;
                        f16x4 h4;
                        h4[0] = (f16)(acc[m][n][0] + bb);
                        h4[1] = (f16)(acc[m][n][1] + bb);
                        h4[2] = (f16)(acc[m][n][2] + bb);
                        h4[3] = (f16)(acc[m][n][3] + bb);
                        const int o = d * RS + (kvl ^ ((d & 7) << 3));
                        *reinterpret_cast<f16x4*>(&smem[o]) = h4;
                    }
                }
            }
            __syncthreads();
            const size_t bh_ = (size_t)batch * HEADS + (n0 >> 6) + s;
            const int row = tid >> 2, c0 = (tid & 3) * 32;
            #pragma unroll
            for (int j = 0; j < 4; ++j) {
                const int so = row * RS + c0 + j * 8;
                const size_t go = bh_ * 131072 + (size_t)row * 2048 + kvg0 + c0 + j * 8;
                *reinterpret_cast<f16x8*>(&F[go]) =
                    *reinterpret_cast<const f16x8*>(&smem[so]);
            }
        }
    }
}

__global__ __launch_bounds__(256) void qkv_kernel(
    const f16* __restrict__ XhG,
    const f16* __restrict__ WqH, const float* __restrict__ bq,
    const f16* __restrict__ WkH, const float* __restrict__ bk,
    const f16* __restrict__ WvH, const float* __restrict__ bv,
    f16* __restrict__ QhG, f16* __restrict__ KhG, f16* __restrict__ VhG)
{
    __shared__ __align__(16) f16 smem[24576];  // 48 KB: 3x16 KB ring / repack
    if (blockIdx.z == 0)
        gemm_plane_body<3>(XhG, WqH, bq, nullptr, QhG, QSCALE, smem);
    else if (blockIdx.z == 1)
        gemm_plane_body<1>(XhG, WkH, bk, nullptr, KhG, 1.0f, smem);
    else
        gemm_plane_body<2>(XhG, WvH, bv, nullptr, VhG, 1.0f, smem);
}

__global__ __launch_bounds__(256) void oproj_kernel(
    const f16* __restrict__ OhG, const f16* __restrict__ WoH,
    const float* __restrict__ bo, float* __restrict__ out)
{
    __shared__ __align__(16) f16 smem[24576];  // 48 KB: 3x16 KB ring
    gemm_plane_body<0>(OhG, WoH, bo, out, nullptr, 1.0f, smem);
}

// ---------------------------------------------------------------------------
// Flash attention v9 (exact R15 revert, proven 48.8 us / 4.88e-4):
// KVBLK=128 staging, two 64-kv compute halves per staged tile, 4 waves,
// QBLK=32/wave, 128 q-rows/block, 512 blocks, 80 KB LDS. Pure-f16 MFMA,
// exp2-folded scores, lsum via ones-MFMA, P via per-wave LDS, XCD swizzle,
// setprio. [R16's QBLK=64 @ 1 block/CU regressed: occupancy loss > LDS
// amortization — do not revisit.]
// ---------------------------------------------------------------------------
__global__ __launch_bounds__(256, 2) void attn_kernel(
    const f16* __restrict__ QhG, const f16* __restrict__ KhG,
    const f16* __restrict__ VhG, f16* __restrict__ OhG)
{
    __shared__ __align__(16) f16 lds[2][2][8192];   // 64 KB: Kh, Vh dbuf (128 kv)
    __shared__ __align__(16) f16 PL[4][2][1024];    // 16 KB per-wave P^T

    const int tid = threadIdx.x;
    const int l   = tid & 63;
    const int w   = tid >> 6;
    const int fr  = l & 15;
    const int g   = l >> 4;
    const int fk  = g * 8;
    const int rg  = g * 4;
    const int swz = (fr & 7) << 3;

    // 512 blocks, 64-block chunks per XCD (4 bh -> 2 MB K+V per XCD L2)
    const int lin  = blockIdx.x + 16 * (blockIdx.y + 16 * blockIdx.z);
    const int sid  = (lin & 7) * 64 + (lin >> 3);
    const int qblk = sid & 15;
    const int head = (sid >> 4) & 15;
    const int batch = sid >> 8;

    const int q0 = qblk * 128;
    const size_t rowbase = (size_t)batch * SEQ;
    const int hcol = head * HD;
    const size_t bhbase = ((size_t)batch * HEADS + head) * (size_t)(SEQ * HD);

    size_t kA[4], vA[4];
    #pragma unroll
    for (int c = 0; c < 4; ++c) {
        const int h0 = (w * 4 + c) * 512 + l * 8;
        kA[c] = bhbase + (size_t)h0;                               // + t*8192
        vA[c] = bhbase + (size_t)(h0 >> 7) * 2048 + (h0 & 127);    // + t*128
    }

#define STAGE(B, T) do {                                                    \
        const size_t _ko = (size_t)(T) * 8192;                              \
        const size_t _vo = (size_t)(T) * 128;                               \
        _Pragma("unroll")                                                   \
        for (int c = 0; c < 4; ++c) {                                       \
            const int lo_ = (w * 4 + c) * 512;                              \
            glds16(KhG + kA[c] + _ko, &lds[B][0][lo_]);                     \
            glds16(VhG + vA[c] + _vo, &lds[B][1][lo_]);                     \
        }                                                                   \
    } while (0)

    STAGE(0, 0);

    // Q fragments (B operand, f16, pre-scaled by log2e/64)
    f16x8 qh[2][2];
    #pragma unroll
    for (int qb = 0; qb < 2; ++qb) {
        const f16* qp = &QhG[(rowbase + q0 + w * 32 + qb * 16 + fr) * DIM + hcol];
        qh[qb][0] = *reinterpret_cast<const f16x8*>(&qp[fk]);
        qh[qb][1] = *reinterpret_cast<const f16x8*>(&qp[32 + fk]);
    }

    f16x8 onesv;
    #pragma unroll
    for (int i = 0; i < 8; ++i) onesv[i] = (f16)1.0f;

    f32x4 ls[2] = {};
    f32x4 oa[4][2] = {};

    int cur = 0;
    for (int t = 0; t < NT2; ++t) {
        asm volatile("s_waitcnt vmcnt(0) lgkmcnt(0)\ns_barrier" ::: "memory");
        if (t + 1 < NT2) STAGE(cur ^ 1, t + 1);

        #pragma unroll
        for (int hh = 0; hh < 2; ++hh) {     // two 64-kv halves
            const f16* Kh = &lds[cur][0][hh * 4096];
            const f16* Vh = &lds[cur][1][hh * 64];

            // ---- S'^T = K Q'^T ----
            f32x4 sa[4][2] = {};
            __builtin_amdgcn_s_setprio(1);
            #pragma unroll
            for (int kvb = 0; kvb < 4; ++kvb) {
                #pragma unroll
                for (int ks = 0; ks < 2; ++ks) {
                    const int o = ((kvb * 16 + fr) * 64 + ks * 32 + fk) ^ swz;
                    const f16x8 kh = *reinterpret_cast<const f16x8*>(&Kh[o]);
                    sa[kvb][0] = MFMA16(kh, qh[0][ks], sa[kvb][0]);
                    sa[kvb][1] = MFMA16(kh, qh[1][ks], sa[kvb][1]);
                }
            }
            __builtin_amdgcn_s_setprio(0);

            // ---- P = 2^s per q-stream, pack, stash in per-wave LDS ----
            f16x8 pf[2][2];
            #pragma unroll
            for (int qb = 0; qb < 2; ++qb) {
                f16* Wh = &PL[w][qb][0];
                #pragma unroll
                for (int kvb = 0; kvb < 4; ++kvb) {
                    const f16x2 p01 = pk_f16(exp2_hw(sa[kvb][qb][0]),
                                             exp2_hw(sa[kvb][qb][1]));
                    const f16x2 p23 = pk_f16(exp2_hw(sa[kvb][qb][2]),
                                             exp2_hw(sa[kvb][qb][3]));
                    f16x4 h4;
                    h4[0] = p01[0]; h4[1] = p01[1]; h4[2] = p23[0]; h4[3] = p23[1];
                    const int po = (fr * 64 + kvb * 16 + rg) ^ swz;
                    *reinterpret_cast<f16x4*>(&Wh[po]) = h4;
                }
                #pragma unroll
                for (int ks = 0; ks < 2; ++ks) {
                    const int ro = (fr * 64 + ks * 32 + fk) ^ swz;
                    pf[qb][ks] = *reinterpret_cast<const f16x8*>(&Wh[ro]);
                }
            }

            // ---- lsum += colsum(P); O^T += V^T P^T ----
            __builtin_amdgcn_s_setprio(1);
            #pragma unroll
            for (int qb = 0; qb < 2; ++qb)
                #pragma unroll
                for (int ks = 0; ks < 2; ++ks)
                    ls[qb] = MFMA16(onesv, pf[qb][ks], ls[qb]);
            #pragma unroll
            for (int db = 0; db < 4; ++db) {
                #pragma unroll
                for (int ks = 0; ks < 2; ++ks) {
                    const int vo = (db * 16 + fr) * 128 + ((ks * 32 + fk) ^ swz);
                    const f16x8 vh = *reinterpret_cast<const f16x8*>(&Vh[vo]);
                    oa[db][0] = MFMA16(vh, pf[0][ks], oa[db][0]);
                    oa[db][1] = MFMA16(vh, pf[1][ks], oa[db][1]);
                }
            }
            __builtin_amdgcn_s_setprio(0);
        }
        cur ^= 1;
    }
#undef STAGE

    // ---- epilogue: O hi plane (swizzled for oproj staging) ----
    #pragma unroll
    for (int qb = 0; qb < 2; ++qb) {
        const float inv = 1.0f / ls[qb][0];
        const size_t row = rowbase + q0 + w * 32 + qb * 16 + fr;
        const int s = ((int)row >> 1) & 3;
        #pragma unroll
        for (int db = 0; db < 4; ++db) {
            f16x4 h4;
            #pragma unroll
            for (int j = 0; j < 4; ++j) h4[j] = (f16)(oa[db][qb][j] * inv);
            const int kg = hcol + db * 16 + rg;
            const size_t o = row * DIM + (kg & ~31) + ((kg & 31) ^ (s << 3));
            *reinterpret_cast<f16x4*>(&OhG[o]) = h4;
        }
    }
}

extern "C" void kernel_launch(void* const* d_in, const int* in_sizes, int n_in,
                              void* d_out, int out_size, void* d_ws, size_t ws_size,
                              hipStream_t stream)
{
    const float* x  = (const float*)d_in[0];
    const float* Wq = (const float*)d_in[1];
    const float* bq = (const float*)d_in[2];
    const float* Wk = (const float*)d_in[3];
    const float* bk = (const float*)d_in[4];
    const float* Wv = (const float*)d_in[5];
    const float* bv = (const float*)d_in[6];
    const float* Wo = (const float*)d_in[7];
    const float* bo = (const float*)d_in[8];
    float* out = (float*)d_out;

    const size_t PS = (size_t)MTOT * DIM;   // 4,194,304 elements
    f16* QhG = (f16*)d_ws;                  // 8 MB each
    f16* KhG = QhG + PS;
    f16* VhG = KhG + PS;
    f16* XhG = VhG + PS;                    // reused as Oh after qkv
    f16* WqH = XhG + PS;                    // 2 MB each below
    f16* WkH = WqH + (size_t)DIM * DIM;
    f16* WvH = WkH + (size_t)DIM * DIM;
    f16* WoH = WvH + (size_t)DIM * DIM;
    f16* OhG = XhG;                         // alias: x consumed before attn

    presplit_kernel<<<8192, 256, 0, stream>>>(x, Wq, Wk, Wv, Wo,
                                              XhG, WqH, WkH, WvH, WoH);

    dim3 gqkv(DIM / 128, MTOT / 128, 3);
    qkv_kernel<<<gqkv, 256, 0, stream>>>(XhG, WqH, bq, WkH, bk, WvH, bv,
                                         QhG, KhG, VhG);

    dim3 gattn(SEQ / 128, HEADS, BATCH);
    attn_kernel<<<gattn, 256, 0, stream>>>(QhG, KhG, VhG, OhG);

    dim3 gout(DIM / 128, MTOT / 128);
    oproj_kernel<<<gout, 256, 0, stream>>>(OhG, WoH, bo, out);
}

// Round 18
// 110.903 us; speedup vs baseline: 1.1318x; 1.0139x over previous
//
#include <hip/hip_runtime.h>
#include <math.h>

typedef _Float16 f16;
typedef _Float16 f16x2 __attribute__((ext_vector_type(2)));
typedef _Float16 f16x4 __attribute__((ext_vector_type(4)));
typedef _Float16 f16x8 __attribute__((ext_vector_type(8)));
typedef float    f32x4 __attribute__((ext_vector_type(4)));

constexpr int DIM   = 1024;
constexpr int HEADS = 16;
constexpr int HD    = 64;
constexpr int BATCH = 2;
constexpr int SEQ   = 2048;
constexpr int MTOT  = BATCH * SEQ;   // 4096
constexpr int NT2   = SEQ / 128;     // 16 staged KV tiles of 128

// exp(q.k/64) == exp2((q * log2e/64) . k): fold into Q projection scale.
#define QSCALE (1.4426950408889634f / 64.0f)

#define MFMA16(a, b, c) __builtin_amdgcn_mfma_f32_16x16x32_f16((a), (b), (c), 0, 0, 0)

__device__ __forceinline__ void glds16(const void* g, void* l) {
    __builtin_amdgcn_global_load_lds(
        (const __attribute__((address_space(1))) void*)g,
        (__attribute__((address_space(3))) void*)l, 16, 0, 0);
}

__device__ __forceinline__ float exp2_hw(float x) {
    float r;
    asm("v_exp_f32 %0, %1" : "=v"(r) : "v"(x));   // D = 2^S0
    return r;
}

__device__ __forceinline__ f16x2 pk_f16(float a, float b) {
    return __builtin_bit_cast(f16x2, __builtin_amdgcn_cvt_pkrtz(a, b));
}

// ---------------------------------------------------------------------------
// Pre-split pass: fp32 -> f16 hi planes, GEMM fragment-read swizzle baked:
// within each 32-half k-tile, 8-half slot ^= ((row>>1)&3).
// ---------------------------------------------------------------------------
__global__ __launch_bounds__(256) void presplit_kernel(
    const float* __restrict__ x,  const float* __restrict__ Wq,
    const float* __restrict__ Wk, const float* __restrict__ Wv,
    const float* __restrict__ Wo,
    f16* __restrict__ Xh,  f16* __restrict__ WqH, f16* __restrict__ WkH,
    f16* __restrict__ WvH, f16* __restrict__ WoH)
{
    const int bid = blockIdx.x;
    const float* src; f16* dh; int row;
    if (bid < 4096)      { src = x;  dh = Xh;  row = bid; }
    else if (bid < 5120) { src = Wq; dh = WqH; row = bid - 4096; }
    else if (bid < 6144) { src = Wk; dh = WkH; row = bid - 5120; }
    else if (bid < 7168) { src = Wv; dh = WvH; row = bid - 6144; }
    else                 { src = Wo; dh = WoH; row = bid - 7168; }

    const int k = threadIdx.x * 4;
    const float4 v = *reinterpret_cast<const float4*>(&src[(size_t)row * DIM + k]);
    const int s = (row >> 1) & 3;
    const size_t o = (size_t)row * DIM + (k & ~31) + ((k & 31) ^ (s << 3));
    f16x4 h4;
    h4[0] = (f16)v.x; h4[1] = (f16)v.y; h4[2] = (f16)v.z; h4[3] = (f16)v.w;
    *reinterpret_cast<f16x4*>(&dh[o]) = h4;
}

// ---------------------------------------------------------------------------
// FUSED QKV: one block computes Q, K, V for the same 128 rows x 128 cols.
// x-tile staged ONCE per k-step (vs 3x unfused): LDS traffic -33%.
// 3-buffer ring, 2-deep prefetch, counted vmcnt (R17 proven schedule);
// each wave stages one plane (w=0:X, 1:Wq, 2:Wk, 3:Wv; 8 glds16/step).
// Per step: 16 frag reads, 48 MFMAs/wave. 256 blocks = 1/CU, 96 KB LDS.
// Epilogues: Q -> f16 plain; K -> [bh][kv][d^swz] (transposed acc);
// V -> [bh][d][kv^swz(within-64)] via LDS repack (bit-identical to unfused).
// ---------------------------------------------------------------------------
__global__ __launch_bounds__(256, 1) void qkv_kernel(
    const f16* __restrict__ XhG,
    const f16* __restrict__ WqH, const float* __restrict__ bq,
    const f16* __restrict__ WkH, const float* __restrict__ bk,
    const f16* __restrict__ WvH, const float* __restrict__ bv,
    f16* __restrict__ QhG, f16* __restrict__ KhG, f16* __restrict__ VhG)
{
    __shared__ __align__(16) f16 smem[49152];   // 96 KB: 3 x 32 KB ring

    const int tid = threadIdx.x;
    const int l   = tid & 63;
    const int w   = tid >> 6;
    const int wm  = (w >> 1) * 64;
    const int wn  = (w & 1) * 64;
    const int m0  = blockIdx.y * 128;
    const int n0  = blockIdx.x * 128;
    const int fr  = l & 15;
    const int fk  = (l >> 4) * 8;
    const int rg  = (l >> 4) * 4;
    const int fko = fk ^ (((fr >> 1) & 3) << 3);

    const f16* Pw = (w == 0) ? XhG : (w == 1) ? WqH : (w == 2) ? WkH : WvH;
    const int  r0w = (w == 0) ? m0 : n0;

    f32x4 accq[4][4] = {}, acck[4][4] = {}, accv[4][4] = {};

#define GSTAGE(B, K0) do {                                                  \
        _Pragma("unroll")                                                   \
        for (int j = 0; j < 8; ++j) {                                       \
            const int row = r0w + j * 16 + (l >> 2);                        \
            glds16(Pw + (size_t)row * DIM + (K0) + (l & 3) * 8,             \
                   smem + (B) * 16384 + w * 4096 + j * 512);                \
        }                                                                   \
    } while (0)

    GSTAGE(0, 0);
    GSTAGE(1, 32);
    int b0 = 0, b1 = 1, b2 = 2;

    for (int k0 = 0; k0 < DIM; k0 += 32) {
        if (k0 + 64 < DIM) {
            GSTAGE(b2, k0 + 64);
            asm volatile("s_waitcnt vmcnt(16)\ns_barrier" ::: "memory");
        } else if (k0 + 32 < DIM) {
            asm volatile("s_waitcnt vmcnt(8)\ns_barrier" ::: "memory");
        } else {
            asm volatile("s_waitcnt vmcnt(0)\ns_barrier" ::: "memory");
        }

        const f16* Bu = smem + b0 * 16384;
        f16x8 ah[4], bqf[4], bkf[4], bvf[4];
        #pragma unroll
        for (int m = 0; m < 4; ++m)
            ah[m] = *reinterpret_cast<const f16x8*>(&Bu[(wm + m * 16 + fr) * 32 + fko]);
        #pragma unroll
        for (int n = 0; n < 4; ++n) {
            const int r = (wn + n * 16 + fr) * 32 + fko;
            bqf[n] = *reinterpret_cast<const f16x8*>(&Bu[4096 + r]);
            bkf[n] = *reinterpret_cast<const f16x8*>(&Bu[8192 + r]);
            bvf[n] = *reinterpret_cast<const f16x8*>(&Bu[12288 + r]);
        }
        #pragma unroll
        for (int n = 0; n < 4; ++n)
            #pragma unroll
            for (int m = 0; m < 4; ++m) {
                accq[m][n] = MFMA16(ah[m], bqf[n], accq[m][n]);
                acck[m][n] = MFMA16(bkf[n], ah[m], acck[m][n]);   // D[d][token]
                accv[m][n] = MFMA16(ah[m], bvf[n], accv[m][n]);
            }
        asm volatile("s_barrier" ::: "memory");
        const int tmp = b0; b0 = b1; b1 = b2; b2 = tmp;
    }
#undef GSTAGE

    // ---- Q epilogue: f16 plain [row][col], scale folded ----
    #pragma unroll
    for (int n = 0; n < 4; ++n) {
        const int col  = n0 + wn + n * 16 + fr;
        const float bb = bq[col];
        #pragma unroll
        for (int m = 0; m < 4; ++m)
            #pragma unroll
            for (int r = 0; r < 4; ++r) {
                const int row = m0 + wm + m * 16 + rg + r;
                QhG[(size_t)row * DIM + col] = (f16)((accq[m][n][r] + bb) * QSCALE);
            }
    }

    const int batch = m0 >> 11;
    const int kvg0  = m0 & 2047;

    // ---- K epilogue: [bh][kv][ d ^ ((kv&7)<<3) ] via LDS repack ----
    {
        constexpr int RS = 72;
        for (int s = 0; s < 2; ++s) {
            __syncthreads();
            if ((w & 1) == s) {
                #pragma unroll
                for (int n = 0; n < 4; ++n) {
                    #pragma unroll
                    for (int m = 0; m < 4; ++m) {
                        const int kvrow = wm + m * 16 + fr;
                        const int dd    = n * 16 + rg;
                        f16x4 h4;
                        #pragma unroll
                        for (int r = 0; r < 4; ++r)
                            h4[r] = (f16)(acck[m][n][r] + bk[n0 + wn + dd + r]);
                        const int o = kvrow * RS + (dd ^ ((kvrow & 7) << 3));
                        *reinterpret_cast<f16x4*>(&smem[o]) = h4;
                    }
                }
            }
            __syncthreads();
            const size_t bh_ = (size_t)batch * HEADS + (n0 >> 6) + s;
            const int row = tid >> 1, c0 = (tid & 1) * 32;
            #pragma unroll
            for (int j = 0; j < 4; ++j) {
                const int so = row * RS + c0 + j * 8;
                const size_t go = bh_ * 131072 + (size_t)(kvg0 + row) * 64 + c0 + j * 8;
                *reinterpret_cast<f16x8*>(&KhG[go]) =
                    *reinterpret_cast<const f16x8*>(&smem[so]);
            }
        }
    }

    // ---- V epilogue: [bh][d][ kv ^ ((d&7)<<3) within-64 ] via LDS repack ----
    {
        constexpr int RS = 136;
        for (int s = 0; s < 2; ++s) {
            __syncthreads();
            if ((w & 1) == s) {
                #pragma unroll
                for (int n = 0; n < 4; ++n) {
                    const int d    = n * 16 + fr;
                    const float bb = bv[n0 + wn + d];
                    #pragma unroll
                    for (int m = 0; m < 4; ++m) {
                        const int kvl = wm + m * 16 + rg;
                        f16x4 h4;
                        h4[0] = (f16)(accv[m][n][0] + bb);
                        h4[1] = (f16)(accv[m][n][1] + bb);
                        h4[2] = (f16)(accv[m][n][2] + bb);
                        h4[3] = (f16)(accv[m][n][3] + bb);
                        const int o = d * RS + (kvl ^ ((d & 7) << 3));
                        *reinterpret_cast<f16x4*>(&smem[o]) = h4;
                    }
                }
            }
            __syncthreads();
            const size_t bh_ = (size_t)batch * HEADS + (n0 >> 6) + s;
            const int row = tid >> 2, c0 = (tid & 3) * 32;
            #pragma unroll
            for (int j = 0; j < 4; ++j) {
                const int so = row * RS + c0 + j * 8;
                const size_t go = bh_ * 131072 + (size_t)row * 2048 + kvg0 + c0 + j * 8;
                *reinterpret_cast<f16x8*>(&VhG[go]) =
                    *reinterpret_cast<const f16x8*>(&smem[so]);
            }
        }
    }
}

// ---------------------------------------------------------------------------
// 1-term plane GEMM (oproj only), BK=32, T4 3-buffer ring, 2-deep prefetch
// (R17 proven). BM=BN=128, 4 waves, LDS 3x16 KB ring.
// ---------------------------------------------------------------------------
__device__ __forceinline__ void gemm_oproj_body(
    const f16* __restrict__ AhG, const f16* __restrict__ BhG,
    const float* __restrict__ bias, float* __restrict__ C,
    f16* __restrict__ smem)
{
    const int tid = threadIdx.x;
    const int l   = tid & 63;
    const int w   = tid >> 6;
    const int wm  = (w >> 1) * 64;
    const int wn  = (w & 1) * 64;
    const int m0  = blockIdx.y * 128;
    const int n0  = blockIdx.x * 128;
    const int fr  = l & 15;
    const int fk  = (l >> 4) * 8;
    const int rg  = (l >> 4) * 4;
    const int fko = fk ^ (((fr >> 1) & 3) << 3);

    f32x4 acc[4][4] = {};

#define GSTAGE(B, K0) do {                                                  \
        _Pragma("unroll")                                                   \
        for (int j = 0; j < 4; ++j) {                                       \
            const int c = w * 4 + j;                                        \
            const int p = c >> 3;                                           \
            const f16* P = (p == 0) ? AhG : BhG;                            \
            const int r0 = (p == 0) ? m0 : n0;                              \
            const int row = r0 + (c & 7) * 16 + (l >> 2);                   \
            glds16(P + (size_t)row * DIM + (K0) + (l & 3) * 8,              \
                   smem + (B) * 8192 + c * 512);                            \
        }                                                                   \
    } while (0)

    GSTAGE(0, 0);
    GSTAGE(1, 32);
    int b0 = 0, b1 = 1, b2 = 2;

    for (int k0 = 0; k0 < DIM; k0 += 32) {
        if (k0 + 64 < DIM) {
            GSTAGE(b2, k0 + 64);
            asm volatile("s_waitcnt vmcnt(8)\ns_barrier" ::: "memory");
        } else if (k0 + 32 < DIM) {
            asm volatile("s_waitcnt vmcnt(4)\ns_barrier" ::: "memory");
        } else {
            asm volatile("s_waitcnt vmcnt(0)\ns_barrier" ::: "memory");
        }

        const f16* Ah = smem + b0 * 8192;
        const f16* Bh = Ah + 4096;

        f16x8 ah[4], bh[4];
        #pragma unroll
        for (int m = 0; m < 4; ++m)
            ah[m] = *reinterpret_cast<const f16x8*>(&Ah[(wm + m * 16 + fr) * 32 + fko]);
        #pragma unroll
        for (int n = 0; n < 4; ++n)
            bh[n] = *reinterpret_cast<const f16x8*>(&Bh[(wn + n * 16 + fr) * 32 + fko]);
        #pragma unroll
        for (int n = 0; n < 4; ++n)
            #pragma unroll
            for (int m = 0; m < 4; ++m)
                acc[m][n] = MFMA16(ah[m], bh[n], acc[m][n]);
        asm volatile("s_barrier" ::: "memory");
        const int tmp = b0; b0 = b1; b1 = b2; b2 = tmp;
    }
#undef GSTAGE

    #pragma unroll
    for (int n = 0; n < 4; ++n) {
        const int col  = n0 + wn + n * 16 + fr;
        const float bb = bias[col];
        #pragma unroll
        for (int m = 0; m < 4; ++m)
            #pragma unroll
            for (int r = 0; r < 4; ++r) {
                const int row = m0 + wm + m * 16 + rg + r;
                C[(size_t)row * DIM + col] = acc[m][n][r] + bb;
            }
    }
}

__global__ __launch_bounds__(256) void oproj_kernel(
    const f16* __restrict__ OhG, const f16* __restrict__ WoH,
    const float* __restrict__ bo, float* __restrict__ out)
{
    __shared__ __align__(16) f16 smem[24576];  // 48 KB: 3x16 KB ring
    gemm_oproj_body(OhG, WoH, bo, out, smem);
}

// ---------------------------------------------------------------------------
// Flash attention v9.1: R15 core (proven 48.8 us / 4.88e-4) with V LDS
// split into two [64][64] sub-planes (stride 64 reads like K) -> V-read
// bank conflicts halved vs the [64][128] stride-128 layout. Values and
// math bit-identical. KVBLK=128 staging, 4 waves, QBLK=32/wave, 512
// blocks, 80 KB LDS, pure-f16 MFMA, exp2 scores, lsum via ones-MFMA.
// ---------------------------------------------------------------------------
__global__ __launch_bounds__(256, 2) void attn_kernel(
    const f16* __restrict__ QhG, const f16* __restrict__ KhG,
    const f16* __restrict__ VhG, f16* __restrict__ OhG)
{
    __shared__ __align__(16) f16 lds[2][2][8192];   // K: [128][64]; V: [2][64][64]
    __shared__ __align__(16) f16 PL[4][2][1024];    // 16 KB per-wave P^T

    const int tid = threadIdx.x;
    const int l   = tid & 63;
    const int w   = tid >> 6;
    const int fr  = l & 15;
    const int g   = l >> 4;
    const int fk  = g * 8;
    const int rg  = g * 4;
    const int swz = (fr & 7) << 3;

    // 512 blocks, 64-block chunks per XCD (4 bh -> 2 MB K+V per XCD L2)
    const int lin  = blockIdx.x + 16 * (blockIdx.y + 16 * blockIdx.z);
    const int sid  = (lin & 7) * 64 + (lin >> 3);
    const int qblk = sid & 15;
    const int head = (sid >> 4) & 15;
    const int batch = sid >> 8;

    const int q0 = qblk * 128;
    const size_t rowbase = (size_t)batch * SEQ;
    const int hcol = head * HD;
    const size_t bhbase = ((size_t)batch * HEADS + head) * (size_t)(SEQ * HD);

    size_t kA[4], vA[4];
    #pragma unroll
    for (int c = 0; c < 4; ++c) {
        const int h0 = (w * 4 + c) * 512 + l * 8;
        kA[c] = bhbase + (size_t)h0;                               // + t*8192
        // V dest [hh][d][kv64]: d = (h0>>6)&63, hh = h0>>12, kv = h0&63
        vA[c] = bhbase + (size_t)((h0 >> 6) & 63) * 2048
              + (size_t)(h0 >> 12) * 64 + (h0 & 63);               // + t*128
    }

#define STAGE(B, T) do {                                                    \
        const size_t _ko = (size_t)(T) * 8192;                              \
        const size_t _vo = (size_t)(T) * 128;                               \
        _Pragma("unroll")                                                   \
        for (int c = 0; c < 4; ++c) {                                       \
            const int lo_ = (w * 4 + c) * 512;                              \
            glds16(KhG + kA[c] + _ko, &lds[B][0][lo_]);                     \
            glds16(VhG + vA[c] + _vo, &lds[B][1][lo_]);                     \
        }                                                                   \
    } while (0)

    STAGE(0, 0);

    // Q fragments (B operand, f16, pre-scaled by log2e/64)
    f16x8 qh[2][2];
    #pragma unroll
    for (int qb = 0; qb < 2; ++qb) {
        const f16* qp = &QhG[(rowbase + q0 + w * 32 + qb * 16 + fr) * DIM + hcol];
        qh[qb][0] = *reinterpret_cast<const f16x8*>(&qp[fk]);
        qh[qb][1] = *reinterpret_cast<const f16x8*>(&qp[32 + fk]);
    }

    f16x8 onesv;
    #pragma unroll
    for (int i = 0; i < 8; ++i) onesv[i] = (f16)1.0f;

    f32x4 ls[2] = {};
    f32x4 oa[4][2] = {};

    int cur = 0;
    for (int t = 0; t < NT2; ++t) {
        asm volatile("s_waitcnt vmcnt(0) lgkmcnt(0)\ns_barrier" ::: "memory");
        if (t + 1 < NT2) STAGE(cur ^ 1, t + 1);

        #pragma unroll
        for (int hh = 0; hh < 2; ++hh) {     // two 64-kv halves
            const f16* Kh = &lds[cur][0][hh * 4096];
            const f16* Vh = &lds[cur][1][hh * 4096];   // sub-plane [64 d][64 kv]

            // ---- S'^T = K Q'^T ----
            f32x4 sa[4][2] = {};
            __builtin_amdgcn_s_setprio(1);
            #pragma unroll
            for (int kvb = 0; kvb < 4; ++kvb) {
                #pragma unroll
                for (int ks = 0; ks < 2; ++ks) {
                    const int o = ((kvb * 16 + fr) * 64 + ks * 32 + fk) ^ swz;
                    const f16x8 kh = *reinterpret_cast<const f16x8*>(&Kh[o]);
                    sa[kvb][0] = MFMA16(kh, qh[0][ks], sa[kvb][0]);
                    sa[kvb][1] = MFMA16(kh, qh[1][ks], sa[kvb][1]);
                }
            }
            __builtin_amdgcn_s_setprio(0);

            // ---- P = 2^s per q-stream, pack, stash in per-wave LDS ----
            f16x8 pf[2][2];
            #pragma unroll
            for (int qb = 0; qb < 2; ++qb) {
                f16* Wh = &PL[w][qb][0];
                #pragma unroll
                for (int kvb = 0; kvb < 4; ++kvb) {
                    const f16x2 p01 = pk_f16(exp2_hw(sa[kvb][qb][0]),
                                             exp2_hw(sa[kvb][qb][1]));
                    const f16x2 p23 = pk_f16(exp2_hw(sa[kvb][qb][2]),
                                             exp2_hw(sa[kvb][qb][3]));
                    f16x4 h4;
                    h4[0] = p01[0]; h4[1] = p01[1]; h4[2] = p23[0]; h4[3] = p23[1];
                    const int po = (fr * 64 + kvb * 16 + rg) ^ swz;
                    *reinterpret_cast<f16x4*>(&Wh[po]) = h4;
                }
                #pragma unroll
                for (int ks = 0; ks < 2; ++ks) {
                    const int ro = (fr * 64 + ks * 32 + fk) ^ swz;
                    pf[qb][ks] = *reinterpret_cast<const f16x8*>(&Wh[ro]);
                }
            }

            // ---- lsum += colsum(P); O^T += V^T P^T ----
            __builtin_amdgcn_s_setprio(1);
            #pragma unroll
            for (int qb = 0; qb < 2; ++qb)
                #pragma unroll
                for (int ks = 0; ks < 2; ++ks)
                    ls[qb] = MFMA16(onesv, pf[qb][ks], ls[qb]);
            #pragma unroll
            for (int db = 0; db < 4; ++db) {
                #pragma unroll
                for (int ks = 0; ks < 2; ++ks) {
                    const int vo = (db * 16 + fr) * 64 + ((ks * 32 + fk) ^ swz);
                    const f16x8 vh = *reinterpret_cast<const f16x8*>(&Vh[vo]);
                    oa[db][0] = MFMA16(vh, pf[0][ks], oa[db][0]);
                    oa[db][1] = MFMA16(vh, pf[1][ks], oa[db][1]);
                }
            }
            __builtin_amdgcn_s_setprio(0);
        }
        cur ^= 1;
    }
#undef STAGE

    // ---- epilogue: O hi plane (swizzled for oproj staging) ----
    #pragma unroll
    for (int qb = 0; qb < 2; ++qb) {
        const float inv = 1.0f / ls[qb][0];
        const size_t row = rowbase + q0 + w * 32 + qb * 16 + fr;
        const int s = ((int)row >> 1) & 3;
        #pragma unroll
        for (int db = 0; db < 4; ++db) {
            f16x4 h4;
            #pragma unroll
            for (int j = 0; j < 4; ++j) h4[j] = (f16)(oa[db][qb][j] * inv);
            const int kg = hcol + db * 16 + rg;
            const size_t o = row * DIM + (kg & ~31) + ((kg & 31) ^ (s << 3));
            *reinterpret_cast<f16x4*>(&OhG[o]) = h4;
        }
    }
}

extern "C" void kernel_launch(void* const* d_in, const int* in_sizes, int n_in,
                              void* d_out, int out_size, void* d_ws, size_t ws_size,
                              hipStream_t stream)
{
    const float* x  = (const float*)d_in[0];
    const float* Wq = (const float*)d_in[1];
    const float* bq = (const float*)d_in[2];
    const float* Wk = (const float*)d_in[3];
    const float* bk = (const float*)d_in[4];
    const float* Wv = (const float*)d_in[5];
    const float* bv = (const float*)d_in[6];
    const float* Wo = (const float*)d_in[7];
    const float* bo = (const float*)d_in[8];
    float* out = (float*)d_out;

    const size_t PS = (size_t)MTOT * DIM;   // 4,194,304 elements
    f16* QhG = (f16*)d_ws;                  // 8 MB each
    f16* KhG = QhG + PS;
    f16* VhG = KhG + PS;
    f16* XhG = VhG + PS;                    // reused as Oh after qkv
    f16* WqH = XhG + PS;                    // 2 MB each below
    f16* WkH = WqH + (size_t)DIM * DIM;
    f16* WvH = WkH + (size_t)DIM * DIM;
    f16* WoH = WvH + (size_t)DIM * DIM;
    f16* OhG = XhG;                         // alias: x consumed before attn

    presplit_kernel<<<8192, 256, 0, stream>>>(x, Wq, Wk, Wv, Wo,
                                              XhG, WqH, WkH, WvH, WoH);

    dim3 gqkv(DIM / 128, MTOT / 128);
    qkv_kernel<<<gqkv, 256, 0, stream>>>(XhG, WqH, bq, WkH, bk, WvH, bv,
                                         QhG, KhG, VhG);

    dim3 gattn(SEQ / 128, HEADS, BATCH);
    attn_kernel<<<gattn, 256, 0, stream>>>(QhG, KhG, VhG, OhG);

    dim3 gout(DIM / 128, MTOT / 128);
    oproj_kernel<<<gout, 256, 0, stream>>>(OhG, WoH, bo, out);
}

// Round 19
// 110.531 us; speedup vs baseline: 1.1356x; 1.0034x over previous
//
#include <hip/hip_runtime.h>
#include <math.h>

typedef _Float16 f16;
typedef _Float16 f16x2 __attribute__((ext_vector_type(2)));
typedef _Float16 f16x4 __attribute__((ext_vector_type(4)));
typedef _Float16 f16x8 __attribute__((ext_vector_type(8)));
typedef float    f32x4 __attribute__((ext_vector_type(4)));

constexpr int DIM   = 1024;
constexpr int HEADS = 16;
constexpr int HD    = 64;
constexpr int BATCH = 2;
constexpr int SEQ   = 2048;
constexpr int MTOT  = BATCH * SEQ;   // 4096
constexpr int NT2   = SEQ / 128;     // 16 staged KV tiles of 128

// exp(q.k/64) == exp2((q * log2e/64) . k): fold into Q projection scale.
#define QSCALE (1.4426950408889634f / 64.0f)

#define MFMA16(a, b, c) __builtin_amdgcn_mfma_f32_16x16x32_f16((a), (b), (c), 0, 0, 0)

__device__ __forceinline__ void glds16(const void* g, void* l) {
    __builtin_amdgcn_global_load_lds(
        (const __attribute__((address_space(1))) void*)g,
        (__attribute__((address_space(3))) void*)l, 16, 0, 0);
}

__device__ __forceinline__ float exp2_hw(float x) {
    float r;
    asm("v_exp_f32 %0, %1" : "=v"(r) : "v"(x));   // D = 2^S0
    return r;
}

__device__ __forceinline__ f16x2 pk_f16(float a, float b) {
    return __builtin_bit_cast(f16x2, __builtin_amdgcn_cvt_pkrtz(a, b));
}

// ---------------------------------------------------------------------------
// Pre-split pass: fp32 -> f16 hi planes, GEMM fragment-read swizzle baked:
// within each 32-half k-tile, 8-half slot ^= ((row>>1)&3).
// ---------------------------------------------------------------------------
__global__ __launch_bounds__(256) void presplit_kernel(
    const float* __restrict__ x,  const float* __restrict__ Wq,
    const float* __restrict__ Wk, const float* __restrict__ Wv,
    const float* __restrict__ Wo,
    f16* __restrict__ Xh,  f16* __restrict__ WqH, f16* __restrict__ WkH,
    f16* __restrict__ WvH, f16* __restrict__ WoH)
{
    const int bid = blockIdx.x;
    const float* src; f16* dh; int row;
    if (bid < 4096)      { src = x;  dh = Xh;  row = bid; }
    else if (bid < 5120) { src = Wq; dh = WqH; row = bid - 4096; }
    else if (bid < 6144) { src = Wk; dh = WkH; row = bid - 5120; }
    else if (bid < 7168) { src = Wv; dh = WvH; row = bid - 6144; }
    else                 { src = Wo; dh = WoH; row = bid - 7168; }

    const int k = threadIdx.x * 4;
    const float4 v = *reinterpret_cast<const float4*>(&src[(size_t)row * DIM + k]);
    const int s = (row >> 1) & 3;
    const size_t o = (size_t)row * DIM + (k & ~31) + ((k & 31) ^ (s << 3));
    f16x4 h4;
    h4[0] = (f16)v.x; h4[1] = (f16)v.y; h4[2] = (f16)v.z; h4[3] = (f16)v.w;
    *reinterpret_cast<f16x4*>(&dh[o]) = h4;
}

// ---------------------------------------------------------------------------
// FUSED QKV (R18 proven): one block computes Q, K, V for the same 128x128.
// x staged once per k-step; 3-buffer ring, 2-deep prefetch, counted vmcnt.
// ---------------------------------------------------------------------------
__global__ __launch_bounds__(256, 1) void qkv_kernel(
    const f16* __restrict__ XhG,
    const f16* __restrict__ WqH, const float* __restrict__ bq,
    const f16* __restrict__ WkH, const float* __restrict__ bk,
    const f16* __restrict__ WvH, const float* __restrict__ bv,
    f16* __restrict__ QhG, f16* __restrict__ KhG, f16* __restrict__ VhG)
{
    __shared__ __align__(16) f16 smem[49152];   // 96 KB: 3 x 32 KB ring

    const int tid = threadIdx.x;
    const int l   = tid & 63;
    const int w   = tid >> 6;
    const int wm  = (w >> 1) * 64;
    const int wn  = (w & 1) * 64;
    const int m0  = blockIdx.y * 128;
    const int n0  = blockIdx.x * 128;
    const int fr  = l & 15;
    const int fk  = (l >> 4) * 8;
    const int rg  = (l >> 4) * 4;
    const int fko = fk ^ (((fr >> 1) & 3) << 3);

    const f16* Pw = (w == 0) ? XhG : (w == 1) ? WqH : (w == 2) ? WkH : WvH;
    const int  r0w = (w == 0) ? m0 : n0;

    f32x4 accq[4][4] = {}, acck[4][4] = {}, accv[4][4] = {};

#define GSTAGE(B, K0) do {                                                  \
        _Pragma("unroll")                                                   \
        for (int j = 0; j < 8; ++j) {                                       \
            const int row = r0w + j * 16 + (l >> 2);                        \
            glds16(Pw + (size_t)row * DIM + (K0) + (l & 3) * 8,             \
                   smem + (B) * 16384 + w * 4096 + j * 512);                \
        }                                                                   \
    } while (0)

    GSTAGE(0, 0);
    GSTAGE(1, 32);
    int b0 = 0, b1 = 1, b2 = 2;

    for (int k0 = 0; k0 < DIM; k0 += 32) {
        if (k0 + 64 < DIM) {
            GSTAGE(b2, k0 + 64);
            asm volatile("s_waitcnt vmcnt(16)\ns_barrier" ::: "memory");
        } else if (k0 + 32 < DIM) {
            asm volatile("s_waitcnt vmcnt(8)\ns_barrier" ::: "memory");
        } else {
            asm volatile("s_waitcnt vmcnt(0)\ns_barrier" ::: "memory");
        }

        const f16* Bu = smem + b0 * 16384;
        f16x8 ah[4], bqf[4], bkf[4], bvf[4];
        #pragma unroll
        for (int m = 0; m < 4; ++m)
            ah[m] = *reinterpret_cast<const f16x8*>(&Bu[(wm + m * 16 + fr) * 32 + fko]);
        #pragma unroll
        for (int n = 0; n < 4; ++n) {
            const int r = (wn + n * 16 + fr) * 32 + fko;
            bqf[n] = *reinterpret_cast<const f16x8*>(&Bu[4096 + r]);
            bkf[n] = *reinterpret_cast<const f16x8*>(&Bu[8192 + r]);
            bvf[n] = *reinterpret_cast<const f16x8*>(&Bu[12288 + r]);
        }
        #pragma unroll
        for (int n = 0; n < 4; ++n)
            #pragma unroll
            for (int m = 0; m < 4; ++m) {
                accq[m][n] = MFMA16(ah[m], bqf[n], accq[m][n]);
                acck[m][n] = MFMA16(bkf[n], ah[m], acck[m][n]);   // D[d][token]
                accv[m][n] = MFMA16(ah[m], bvf[n], accv[m][n]);
            }
        asm volatile("s_barrier" ::: "memory");
        const int tmp = b0; b0 = b1; b1 = b2; b2 = tmp;
    }
#undef GSTAGE

    // ---- Q epilogue: f16 plain [row][col], scale folded ----
    #pragma unroll
    for (int n = 0; n < 4; ++n) {
        const int col  = n0 + wn + n * 16 + fr;
        const float bb = bq[col];
        #pragma unroll
        for (int m = 0; m < 4; ++m)
            #pragma unroll
            for (int r = 0; r < 4; ++r) {
                const int row = m0 + wm + m * 16 + rg + r;
                QhG[(size_t)row * DIM + col] = (f16)((accq[m][n][r] + bb) * QSCALE);
            }
    }

    const int batch = m0 >> 11;
    const int kvg0  = m0 & 2047;

    // ---- K epilogue: [bh][kv][ d ^ ((kv&7)<<3) ] via LDS repack ----
    {
        constexpr int RS = 72;
        for (int s = 0; s < 2; ++s) {
            __syncthreads();
            if ((w & 1) == s) {
                #pragma unroll
                for (int n = 0; n < 4; ++n) {
                    #pragma unroll
                    for (int m = 0; m < 4; ++m) {
                        const int kvrow = wm + m * 16 + fr;
                        const int dd    = n * 16 + rg;
                        f16x4 h4;
                        #pragma unroll
                        for (int r = 0; r < 4; ++r)
                            h4[r] = (f16)(acck[m][n][r] + bk[n0 + wn + dd + r]);
                        const int o = kvrow * RS + (dd ^ ((kvrow & 7) << 3));
                        *reinterpret_cast<f16x4*>(&smem[o]) = h4;
                    }
                }
            }
            __syncthreads();
            const size_t bh_ = (size_t)batch * HEADS + (n0 >> 6) + s;
            const int row = tid >> 1, c0 = (tid & 1) * 32;
            #pragma unroll
            for (int j = 0; j < 4; ++j) {
                const int so = row * RS + c0 + j * 8;
                const size_t go = bh_ * 131072 + (size_t)(kvg0 + row) * 64 + c0 + j * 8;
                *reinterpret_cast<f16x8*>(&KhG[go]) =
                    *reinterpret_cast<const f16x8*>(&smem[so]);
            }
        }
    }

    // ---- V epilogue: [bh][d][ kv ^ ((d&7)<<3) within-64 ] via LDS repack ----
    {
        constexpr int RS = 136;
        for (int s = 0; s < 2; ++s) {
            __syncthreads();
            if ((w & 1) == s) {
                #pragma unroll
                for (int n = 0; n < 4; ++n) {
                    const int d    = n * 16 + fr;
                    const float bb = bv[n0 + wn + d];
                    #pragma unroll
                    for (int m = 0; m < 4; ++m) {
                        const int kvl = wm + m * 16 + rg;
                        f16x4 h4;
                        h4[0] = (f16)(accv[m][n][0] + bb);
                        h4[1] = (f16)(accv[m][n][1] + bb);
                        h4[2] = (f16)(accv[m][n][2] + bb);
                        h4[3] = (f16)(accv[m][n][3] + bb);
                        const int o = d * RS + (kvl ^ ((d & 7) << 3));
                        *reinterpret_cast<f16x4*>(&smem[o]) = h4;
                    }
                }
            }
            __syncthreads();
            const size_t bh_ = (size_t)batch * HEADS + (n0 >> 6) + s;
            const int row = tid >> 2, c0 = (tid & 3) * 32;
            #pragma unroll
            for (int j = 0; j < 4; ++j) {
                const int so = row * RS + c0 + j * 8;
                const size_t go = bh_ * 131072 + (size_t)row * 2048 + kvg0 + c0 + j * 8;
                *reinterpret_cast<f16x8*>(&VhG[go]) =
                    *reinterpret_cast<const f16x8*>(&smem[so]);
            }
        }
    }
}

// ---------------------------------------------------------------------------
// 1-term plane GEMM (oproj only), BK=32, T4 3-buffer ring, 2-deep prefetch.
// ---------------------------------------------------------------------------
__device__ __forceinline__ void gemm_oproj_body(
    const f16* __restrict__ AhG, const f16* __restrict__ BhG,
    const float* __restrict__ bias, float* __restrict__ C,
    f16* __restrict__ smem)
{
    const int tid = threadIdx.x;
    const int l   = tid & 63;
    const int w   = tid >> 6;
    const int wm  = (w >> 1) * 64;
    const int wn  = (w & 1) * 64;
    const int m0  = blockIdx.y * 128;
    const int n0  = blockIdx.x * 128;
    const int fr  = l & 15;
    const int fk  = (l >> 4) * 8;
    const int rg  = (l >> 4) * 4;
    const int fko = fk ^ (((fr >> 1) & 3) << 3);

    f32x4 acc[4][4] = {};

#define GSTAGE(B, K0) do {                                                  \
        _Pragma("unroll")                                                   \
        for (int j = 0; j < 4; ++j) {                                       \
            const int c = w * 4 + j;                                        \
            const int p = c >> 3;                                           \
            const f16* P = (p == 0) ? AhG : BhG;                            \
            const int r0 = (p == 0) ? m0 : n0;                              \
            const int row = r0 + (c & 7) * 16 + (l >> 2);                   \
            glds16(P + (size_t)row * DIM + (K0) + (l & 3) * 8,              \
                   smem + (B) * 8192 + c * 512);                            \
        }                                                                   \
    } while (0)

    GSTAGE(0, 0);
    GSTAGE(1, 32);
    int b0 = 0, b1 = 1, b2 = 2;

    for (int k0 = 0; k0 < DIM; k0 += 32) {
        if (k0 + 64 < DIM) {
            GSTAGE(b2, k0 + 64);
            asm volatile("s_waitcnt vmcnt(8)\ns_barrier" ::: "memory");
        } else if (k0 + 32 < DIM) {
            asm volatile("s_waitcnt vmcnt(4)\ns_barrier" ::: "memory");
        } else {
            asm volatile("s_waitcnt vmcnt(0)\ns_barrier" ::: "memory");
        }

        const f16* Ah = smem + b0 * 8192;
        const f16* Bh = Ah + 4096;

        f16x8 ah[4], bh[4];
        #pragma unroll
        for (int m = 0; m < 4; ++m)
            ah[m] = *reinterpret_cast<const f16x8*>(&Ah[(wm + m * 16 + fr) * 32 + fko]);
        #pragma unroll
        for (int n = 0; n < 4; ++n)
            bh[n] = *reinterpret_cast<const f16x8*>(&Bh[(wn + n * 16 + fr) * 32 + fko]);
        #pragma unroll
        for (int n = 0; n < 4; ++n)
            #pragma unroll
            for (int m = 0; m < 4; ++m)
                acc[m][n] = MFMA16(ah[m], bh[n], acc[m][n]);
        asm volatile("s_barrier" ::: "memory");
        const int tmp = b0; b0 = b1; b1 = b2; b2 = tmp;
    }
#undef GSTAGE

    #pragma unroll
    for (int n = 0; n < 4; ++n) {
        const int col  = n0 + wn + n * 16 + fr;
        const float bb = bias[col];
        #pragma unroll
        for (int m = 0; m < 4; ++m)
            #pragma unroll
            for (int r = 0; r < 4; ++r) {
                const int row = m0 + wm + m * 16 + rg + r;
                C[(size_t)row * DIM + col] = acc[m][n][r] + bb;
            }
    }
}

__global__ __launch_bounds__(256) void oproj_kernel(
    const f16* __restrict__ OhG, const f16* __restrict__ WoH,
    const float* __restrict__ bo, float* __restrict__ out)
{
    __shared__ __align__(16) f16 smem[24576];  // 48 KB: 3x16 KB ring
    gemm_oproj_body(OhG, WoH, bo, out, smem);
}

// ---------------------------------------------------------------------------
// Flash attention v9.2: R18 core with counted-vmcnt staging schedule
// (R15-GEMM-proven): per tile {STAGE(t+1); vmcnt(8); s_barrier; compute;
// s_barrier} — prefetch stays in flight across compute, no lgkm drain.
// Dbuf depth unchanged (80 KB LDS, 2 blocks/CU). Math bit-identical.
// ---------------------------------------------------------------------------
__global__ __launch_bounds__(256, 2) void attn_kernel(
    const f16* __restrict__ QhG, const f16* __restrict__ KhG,
    const f16* __restrict__ VhG, f16* __restrict__ OhG)
{
    __shared__ __align__(16) f16 lds[2][2][8192];   // K: [128][64]; V: [2][64][64]
    __shared__ __align__(16) f16 PL[4][2][1024];    // 16 KB per-wave P^T

    const int tid = threadIdx.x;
    const int l   = tid & 63;
    const int w   = tid >> 6;
    const int fr  = l & 15;
    const int g   = l >> 4;
    const int fk  = g * 8;
    const int rg  = g * 4;
    const int swz = (fr & 7) << 3;

    // 512 blocks, 64-block chunks per XCD (4 bh -> 2 MB K+V per XCD L2)
    const int lin  = blockIdx.x + 16 * (blockIdx.y + 16 * blockIdx.z);
    const int sid  = (lin & 7) * 64 + (lin >> 3);
    const int qblk = sid & 15;
    const int head = (sid >> 4) & 15;
    const int batch = sid >> 8;

    const int q0 = qblk * 128;
    const size_t rowbase = (size_t)batch * SEQ;
    const int hcol = head * HD;
    const size_t bhbase = ((size_t)batch * HEADS + head) * (size_t)(SEQ * HD);

    size_t kA[4], vA[4];
    #pragma unroll
    for (int c = 0; c < 4; ++c) {
        const int h0 = (w * 4 + c) * 512 + l * 8;
        kA[c] = bhbase + (size_t)h0;                               // + t*8192
        vA[c] = bhbase + (size_t)((h0 >> 6) & 63) * 2048
              + (size_t)(h0 >> 12) * 64 + (h0 & 63);               // + t*128
    }

#define STAGE(B, T) do {                                                    \
        const size_t _ko = (size_t)(T) * 8192;                              \
        const size_t _vo = (size_t)(T) * 128;                               \
        _Pragma("unroll")                                                   \
        for (int c = 0; c < 4; ++c) {                                       \
            const int lo_ = (w * 4 + c) * 512;                              \
            glds16(KhG + kA[c] + _ko, &lds[B][0][lo_]);                     \
            glds16(VhG + vA[c] + _vo, &lds[B][1][lo_]);                     \
        }                                                                   \
    } while (0)

    STAGE(0, 0);

    // Q fragments (B operand, f16, pre-scaled by log2e/64)
    f16x8 qh[2][2];
    #pragma unroll
    for (int qb = 0; qb < 2; ++qb) {
        const f16* qp = &QhG[(rowbase + q0 + w * 32 + qb * 16 + fr) * DIM + hcol];
        qh[qb][0] = *reinterpret_cast<const f16x8*>(&qp[fk]);
        qh[qb][1] = *reinterpret_cast<const f16x8*>(&qp[32 + fk]);
    }

    f16x8 onesv;
    #pragma unroll
    for (int i = 0; i < 8; ++i) onesv[i] = (f16)1.0f;

    f32x4 ls[2] = {};
    f32x4 oa[4][2] = {};

    int cur = 0;
    for (int t = 0; t < NT2; ++t) {
        if (t + 1 < NT2) {
            STAGE(cur ^ 1, t + 1);   // 8 loads/wave stay in flight over compute
            asm volatile("s_waitcnt vmcnt(8)\ns_barrier" ::: "memory");
        } else {
            asm volatile("s_waitcnt vmcnt(0)\ns_barrier" ::: "memory");
        }

        #pragma unroll
        for (int hh = 0; hh < 2; ++hh) {     // two 64-kv halves
            const f16* Kh = &lds[cur][0][hh * 4096];
            const f16* Vh = &lds[cur][1][hh * 4096];   // sub-plane [64 d][64 kv]

            // ---- S'^T = K Q'^T ----
            f32x4 sa[4][2] = {};
            __builtin_amdgcn_s_setprio(1);
            #pragma unroll
            for (int kvb = 0; kvb < 4; ++kvb) {
                #pragma unroll
                for (int ks = 0; ks < 2; ++ks) {
                    const int o = ((kvb * 16 + fr) * 64 + ks * 32 + fk) ^ swz;
                    const f16x8 kh = *reinterpret_cast<const f16x8*>(&Kh[o]);
                    sa[kvb][0] = MFMA16(kh, qh[0][ks], sa[kvb][0]);
                    sa[kvb][1] = MFMA16(kh, qh[1][ks], sa[kvb][1]);
                }
            }
            __builtin_amdgcn_s_setprio(0);

            // ---- P = 2^s per q-stream, pack, stash in per-wave LDS ----
            f16x8 pf[2][2];
            #pragma unroll
            for (int qb = 0; qb < 2; ++qb) {
                f16* Wh = &PL[w][qb][0];
                #pragma unroll
                for (int kvb = 0; kvb < 4; ++kvb) {
                    const f16x2 p01 = pk_f16(exp2_hw(sa[kvb][qb][0]),
                                             exp2_hw(sa[kvb][qb][1]));
                    const f16x2 p23 = pk_f16(exp2_hw(sa[kvb][qb][2]),
                                             exp2_hw(sa[kvb][qb][3]));
                    f16x4 h4;
                    h4[0] = p01[0]; h4[1] = p01[1]; h4[2] = p23[0]; h4[3] = p23[1];
                    const int po = (fr * 64 + kvb * 16 + rg) ^ swz;
                    *reinterpret_cast<f16x4*>(&Wh[po]) = h4;
                }
                #pragma unroll
                for (int ks = 0; ks < 2; ++ks) {
                    const int ro = (fr * 64 + ks * 32 + fk) ^ swz;
                    pf[qb][ks] = *reinterpret_cast<const f16x8*>(&Wh[ro]);
                }
            }

            // ---- lsum += colsum(P); O^T += V^T P^T ----
            __builtin_amdgcn_s_setprio(1);
            #pragma unroll
            for (int qb = 0; qb < 2; ++qb)
                #pragma unroll
                for (int ks = 0; ks < 2; ++ks)
                    ls[qb] = MFMA16(onesv, pf[qb][ks], ls[qb]);
            #pragma unroll
            for (int db = 0; db < 4; ++db) {
                #pragma unroll
                for (int ks = 0; ks < 2; ++ks) {
                    const int vo = (db * 16 + fr) * 64 + ((ks * 32 + fk) ^ swz);
                    const f16x8 vh = *reinterpret_cast<const f16x8*>(&Vh[vo]);
                    oa[db][0] = MFMA16(vh, pf[0][ks], oa[db][0]);
                    oa[db][1] = MFMA16(vh, pf[1][ks], oa[db][1]);
                }
            }
            __builtin_amdgcn_s_setprio(0);
        }
        // all waves done reading lds[cur] before next iter's STAGE overwrites it
        asm volatile("s_barrier" ::: "memory");
        cur ^= 1;
    }
#undef STAGE

    // ---- epilogue: O hi plane (swizzled for oproj staging) ----
    #pragma unroll
    for (int qb = 0; qb < 2; ++qb) {
        const float inv = 1.0f / ls[qb][0];
        const size_t row = rowbase + q0 + w * 32 + qb * 16 + fr;
        const int s = ((int)row >> 1) & 3;
        #pragma unroll
        for (int db = 0; db < 4; ++db) {
            f16x4 h4;
            #pragma unroll
            for (int j = 0; j < 4; ++j) h4[j] = (f16)(oa[db][qb][j] * inv);
            const int kg = hcol + db * 16 + rg;
            const size_t o = row * DIM + (kg & ~31) + ((kg & 31) ^ (s << 3));
            *reinterpret_cast<f16x4*>(&OhG[o]) = h4;
        }
    }
}

extern "C" void kernel_launch(void* const* d_in, const int* in_sizes, int n_in,
                              void* d_out, int out_size, void* d_ws, size_t ws_size,
                              hipStream_t stream)
{
    const float* x  = (const float*)d_in[0];
    const float* Wq = (const float*)d_in[1];
    const float* bq = (const float*)d_in[2];
    const float* Wk = (const float*)d_in[3];
    const float* bk = (const float*)d_in[4];
    const float* Wv = (const float*)d_in[5];
    const float* bv = (const float*)d_in[6];
    const float* Wo = (const float*)d_in[7];
    const float* bo = (const float*)d_in[8];
    float* out = (float*)d_out;

    const size_t PS = (size_t)MTOT * DIM;   // 4,194,304 elements
    f16* QhG = (f16*)d_ws;                  // 8 MB each
    f16* KhG = QhG + PS;
    f16* VhG = KhG + PS;
    f16* XhG = VhG + PS;                    // reused as Oh after qkv
    f16* WqH = XhG + PS;                    // 2 MB each below
    f16* WkH = WqH + (size_t)DIM * DIM;
    f16* WvH = WkH + (size_t)DIM * DIM;
    f16* WoH = WvH + (size_t)DIM * DIM;
    f16* OhG = XhG;                         // alias: x consumed before attn

    presplit_kernel<<<8192, 256, 0, stream>>>(x, Wq, Wk, Wv, Wo,
                                              XhG, WqH, WkH, WvH, WoH);

    dim3 gqkv(DIM / 128, MTOT / 128);
    qkv_kernel<<<gqkv, 256, 0, stream>>>(XhG, WqH, bq, WkH, bk, WvH, bv,
                                         QhG, KhG, VhG);

    dim3 gattn(SEQ / 128, HEADS, BATCH);
    attn_kernel<<<gattn, 256, 0, stream>>>(QhG, KhG, VhG, OhG);

    dim3 gout(DIM / 128, MTOT / 128);
    oproj_kernel<<<gout, 256, 0, stream>>>(OhG, WoH, bo, out);
}

// Round 20
// 109.909 us; speedup vs baseline: 1.1420x; 1.0057x over previous
//
#include <hip/hip_runtime.h>
#include <math.h>

typedef _Float16 f16;
typedef _Float16 f16x2 __attribute__((ext_vector_type(2)));
typedef _Float16 f16x4 __attribute__((ext_vector_type(4)));
typedef _Float16 f16x8 __attribute__((ext_vector_type(8)));
typedef float    f32x4 __attribute__((ext_vector_type(4)));

constexpr int DIM   = 1024;
constexpr int HEADS = 16;
constexpr int HD    = 64;
constexpr int BATCH = 2;
constexpr int SEQ   = 2048;
constexpr int MTOT  = BATCH * SEQ;   // 4096
constexpr int NT2   = SEQ / 128;     // 16 staged KV tiles of 128

// exp(q.k/64) == exp2((q * log2e/64) . k): fold into Q projection scale.
#define QSCALE (1.4426950408889634f / 64.0f)

#define MFMA16(a, b, c) __builtin_amdgcn_mfma_f32_16x16x32_f16((a), (b), (c), 0, 0, 0)

__device__ __forceinline__ void glds16(const void* g, void* l) {
    __builtin_amdgcn_global_load_lds(
        (const __attribute__((address_space(1))) void*)g,
        (__attribute__((address_space(3))) void*)l, 16, 0, 0);
}

__device__ __forceinline__ float exp2_hw(float x) {
    float r;
    asm("v_exp_f32 %0, %1" : "=v"(r) : "v"(x));   // D = 2^S0
    return r;
}

__device__ __forceinline__ f16x2 pk_f16(float a, float b) {
    return __builtin_bit_cast(f16x2, __builtin_amdgcn_cvt_pkrtz(a, b));
}

// ---------------------------------------------------------------------------
// Pre-split pass: fp32 -> f16 hi planes, GEMM fragment-read swizzle baked:
// within each 32-half k-tile, 8-half slot ^= ((row>>1)&3).
// ---------------------------------------------------------------------------
__global__ __launch_bounds__(256) void presplit_kernel(
    const float* __restrict__ x,  const float* __restrict__ Wq,
    const float* __restrict__ Wk, const float* __restrict__ Wv,
    const float* __restrict__ Wo,
    f16* __restrict__ Xh,  f16* __restrict__ WqH, f16* __restrict__ WkH,
    f16* __restrict__ WvH, f16* __restrict__ WoH)
{
    const int bid = blockIdx.x;
    const float* src; f16* dh; int row;
    if (bid < 4096)      { src = x;  dh = Xh;  row = bid; }
    else if (bid < 5120) { src = Wq; dh = WqH; row = bid - 4096; }
    else if (bid < 6144) { src = Wk; dh = WkH; row = bid - 5120; }
    else if (bid < 7168) { src = Wv; dh = WvH; row = bid - 6144; }
    else                 { src = Wo; dh = WoH; row = bid - 7168; }

    const int k = threadIdx.x * 4;
    const float4 v = *reinterpret_cast<const float4*>(&src[(size_t)row * DIM + k]);
    const int s = (row >> 1) & 3;
    const size_t o = (size_t)row * DIM + (k & ~31) + ((k & 31) ^ (s << 3));
    f16x4 h4;
    h4[0] = (f16)v.x; h4[1] = (f16)v.y; h4[2] = (f16)v.z; h4[3] = (f16)v.w;
    *reinterpret_cast<f16x4*>(&dh[o]) = h4;
}

// ---------------------------------------------------------------------------
// FUSED QKV v2: BM=128 x BN=64 (one head per block), 512 blocks = 2/CU
// (2 waves/SIMD vs R18's 1 — latency now covered by TLP). x staged once
// per k-step; 3-buffer ring (3 x 20 KB = 60 KB), 2-deep prefetch, counted
// vmcnt. 4 waves tile [128 tok]x[64 col] as 2x2 of 64x32; 24 MFMA/step.
// Epilogues: Q f16 plain; K [bh][kv][d^swz]; V [bh][d][kv^swz(64)] — single
// head, no 2-slot serialization. Math bit-identical to R18.
// ---------------------------------------------------------------------------
__global__ __launch_bounds__(256, 2) void qkv_kernel(
    const f16* __restrict__ XhG,
    const f16* __restrict__ WqH, const float* __restrict__ bq,
    const f16* __restrict__ WkH, const float* __restrict__ bk,
    const f16* __restrict__ WvH, const float* __restrict__ bv,
    f16* __restrict__ QhG, f16* __restrict__ KhG, f16* __restrict__ VhG)
{
    __shared__ __align__(16) f16 smem[30720];   // 60 KB: 3 x 10240-half ring

    const int tid = threadIdx.x;
    const int l   = tid & 63;
    const int w   = tid >> 6;
    const int wm  = (w >> 1) * 64;      // token offset
    const int wn  = (w & 1) * 32;       // col offset within head
    const int m0  = blockIdx.y * 128;
    const int n0  = blockIdx.x * 64;    // one head
    const int fr  = l & 15;
    const int fk  = (l >> 4) * 8;
    const int rg  = (l >> 4) * 4;
    const int fko = fk ^ (((fr >> 1) & 3) << 3);

    f32x4 accq[4][2] = {}, acck[4][2] = {}, accv[4][2] = {};

    // 20 chunks of 512 halves: 0-7 x (16 rows ea), 8-19 W planes (4 ea).
#define GSTAGE(B, K0) do {                                                  \
        _Pragma("unroll")                                                   \
        for (int j = 0; j < 5; ++j) {                                       \
            const int c = w * 5 + j;                                        \
            const f16* P; int row, dst;                                     \
            if (c < 8) {                                                    \
                P = XhG; row = m0 + c * 16 + (l >> 2); dst = c * 512;       \
            } else {                                                        \
                const int p  = (c - 8) >> 2;                                \
                const int cc = (c - 8) & 3;                                 \
                P = (p == 0) ? WqH : (p == 1) ? WkH : WvH;                  \
                row = n0 + cc * 16 + (l >> 2);                              \
                dst = 4096 + p * 2048 + cc * 512;                           \
            }                                                               \
            glds16(P + (size_t)row * DIM + (K0) + (l & 3) * 8,              \
                   smem + (B) * 10240 + dst);                               \
        }                                                                   \
    } while (0)

    GSTAGE(0, 0);
    GSTAGE(1, 32);
    int b0 = 0, b1 = 1, b2 = 2;

    for (int k0 = 0; k0 < DIM; k0 += 32) {
        if (k0 + 64 < DIM) {
            GSTAGE(b2, k0 + 64);
            asm volatile("s_waitcnt vmcnt(10)\ns_barrier" ::: "memory");
        } else if (k0 + 32 < DIM) {
            asm volatile("s_waitcnt vmcnt(5)\ns_barrier" ::: "memory");
        } else {
            asm volatile("s_waitcnt vmcnt(0)\ns_barrier" ::: "memory");
        }

        const f16* Bu = smem + b0 * 10240;
        f16x8 ah[4], bqf[2], bkf[2], bvf[2];
        #pragma unroll
        for (int m = 0; m < 4; ++m)
            ah[m] = *reinterpret_cast<const f16x8*>(&Bu[(wm + m * 16 + fr) * 32 + fko]);
        #pragma unroll
        for (int n = 0; n < 2; ++n) {
            const int r = (wn + n * 16 + fr) * 32 + fko;
            bqf[n] = *reinterpret_cast<const f16x8*>(&Bu[4096 + r]);
            bkf[n] = *reinterpret_cast<const f16x8*>(&Bu[6144 + r]);
            bvf[n] = *reinterpret_cast<const f16x8*>(&Bu[8192 + r]);
        }
        #pragma unroll
        for (int n = 0; n < 2; ++n)
            #pragma unroll
            for (int m = 0; m < 4; ++m) {
                accq[m][n] = MFMA16(ah[m], bqf[n], accq[m][n]);
                acck[m][n] = MFMA16(bkf[n], ah[m], acck[m][n]);   // D[d][token]
                accv[m][n] = MFMA16(ah[m], bvf[n], accv[m][n]);
            }
        asm volatile("s_barrier" ::: "memory");
        const int tmp = b0; b0 = b1; b1 = b2; b2 = tmp;
    }
#undef GSTAGE

    // ---- Q epilogue: f16 plain [row][col], scale folded ----
    #pragma unroll
    for (int n = 0; n < 2; ++n) {
        const int col  = n0 + wn + n * 16 + fr;
        const float bb = bq[col];
        #pragma unroll
        for (int m = 0; m < 4; ++m)
            #pragma unroll
            for (int r = 0; r < 4; ++r) {
                const int row = m0 + wm + m * 16 + rg + r;
                QhG[(size_t)row * DIM + col] = (f16)((accq[m][n][r] + bb) * QSCALE);
            }
    }

    const int batch = m0 >> 11;
    const int kvg0  = m0 & 2047;
    const size_t bh_ = (size_t)batch * HEADS + (n0 >> 6);

    // ---- K epilogue: [bh][kv][ d ^ ((kv&7)<<3) ] via LDS repack ----
    {
        constexpr int RS = 72;
        #pragma unroll
        for (int n = 0; n < 2; ++n) {
            #pragma unroll
            for (int m = 0; m < 4; ++m) {
                const int kvrow = wm + m * 16 + fr;
                const int dd    = wn + n * 16 + rg;
                f16x4 h4;
                #pragma unroll
                for (int r = 0; r < 4; ++r)
                    h4[r] = (f16)(acck[m][n][r] + bk[n0 + dd + r]);
                const int o = kvrow * RS + (dd ^ ((kvrow & 7) << 3));
                *reinterpret_cast<f16x4*>(&smem[o]) = h4;
            }
        }
        __syncthreads();
        const int row = tid >> 1, c0 = (tid & 1) * 32;
        #pragma unroll
        for (int j = 0; j < 4; ++j) {
            const int so = row * RS + c0 + j * 8;
            const size_t go = bh_ * 131072 + (size_t)(kvg0 + row) * 64 + c0 + j * 8;
            *reinterpret_cast<f16x8*>(&KhG[go]) =
                *reinterpret_cast<const f16x8*>(&smem[so]);
        }
        __syncthreads();
    }

    // ---- V epilogue: [bh][d][ kv ^ ((d&7)<<3) ] via LDS repack ----
    {
        constexpr int RS = 136;
        #pragma unroll
        for (int n = 0; n < 2; ++n) {
            const int d    = wn + n * 16 + fr;
            const float bb = bv[n0 + d];
            #pragma unroll
            for (int m = 0; m < 4; ++m) {
                const int kvl = wm + m * 16 + rg;
                f16x4 h4;
                h4[0] = (f16)(accv[m][n][0] + bb);
                h4[1] = (f16)(accv[m][n][1] + bb);
                h4[2] = (f16)(accv[m][n][2] + bb);
                h4[3] = (f16)(accv[m][n][3] + bb);
                const int o = d * RS + (kvl ^ ((d & 7) << 3));
                *reinterpret_cast<f16x4*>(&smem[o]) = h4;
            }
        }
        __syncthreads();
        const int row = tid >> 2, c0 = (tid & 3) * 32;
        #pragma unroll
        for (int j = 0; j < 4; ++j) {
            const int so = row * RS + c0 + j * 8;
            const size_t go = bh_ * 131072 + (size_t)row * 2048 + kvg0 + c0 + j * 8;
            *reinterpret_cast<f16x8*>(&VhG[go]) =
                *reinterpret_cast<const f16x8*>(&smem[so]);
        }
    }
}

// ---------------------------------------------------------------------------
// oproj v2: BM=128 x BN=64, 512 blocks = 2/CU. 3-buffer ring (3x12 KB),
// 2-deep prefetch, counted vmcnt. 4 waves 2x2 over 128x64; 8 MFMA/step.
// ---------------------------------------------------------------------------
__global__ __launch_bounds__(256, 2) void oproj_kernel(
    const f16* __restrict__ OhG, const f16* __restrict__ WoH,
    const float* __restrict__ bo, float* __restrict__ out)
{
    __shared__ __align__(16) f16 smem[18432];   // 36 KB: 3 x 6144-half ring

    const int tid = threadIdx.x;
    const int l   = tid & 63;
    const int w   = tid >> 6;
    const int wm  = (w >> 1) * 64;
    const int wn  = (w & 1) * 32;
    const int m0  = blockIdx.y * 128;
    const int n0  = blockIdx.x * 64;
    const int fr  = l & 15;
    const int fk  = (l >> 4) * 8;
    const int rg  = (l >> 4) * 4;
    const int fko = fk ^ (((fr >> 1) & 3) << 3);

    f32x4 acc[4][2] = {};

    // 12 chunks: 0-7 A (16 rows ea), 8-11 B.
#define GSTAGE(B, K0) do {                                                  \
        _Pragma("unroll")                                                   \
        for (int j = 0; j < 3; ++j) {                                       \
            const int c = w * 3 + j;                                        \
            const f16* P; int row, dst;                                     \
            if (c < 8) { P = OhG; row = m0 + c * 16 + (l >> 2); dst = c * 512; } \
            else { P = WoH; row = n0 + (c - 8) * 16 + (l >> 2);             \
                   dst = 4096 + (c - 8) * 512; }                            \
            glds16(P + (size_t)row * DIM + (K0) + (l & 3) * 8,              \
                   smem + (B) * 6144 + dst);                                \
        }                                                                   \
    } while (0)

    GSTAGE(0, 0);
    GSTAGE(1, 32);
    int b0 = 0, b1 = 1, b2 = 2;

    for (int k0 = 0; k0 < DIM; k0 += 32) {
        if (k0 + 64 < DIM) {
            GSTAGE(b2, k0 + 64);
            asm volatile("s_waitcnt vmcnt(6)\ns_barrier" ::: "memory");
        } else if (k0 + 32 < DIM) {
            asm volatile("s_waitcnt vmcnt(3)\ns_barrier" ::: "memory");
        } else {
            asm volatile("s_waitcnt vmcnt(0)\ns_barrier" ::: "memory");
        }

        const f16* Ah = smem + b0 * 6144;
        const f16* Bh = Ah + 4096;

        f16x8 ah[4], bh[2];
        #pragma unroll
        for (int m = 0; m < 4; ++m)
            ah[m] = *reinterpret_cast<const f16x8*>(&Ah[(wm + m * 16 + fr) * 32 + fko]);
        #pragma unroll
        for (int n = 0; n < 2; ++n)
            bh[n] = *reinterpret_cast<const f16x8*>(&Bh[(wn + n * 16 + fr) * 32 + fko]);
        #pragma unroll
        for (int n = 0; n < 2; ++n)
            #pragma unroll
            for (int m = 0; m < 4; ++m)
                acc[m][n] = MFMA16(ah[m], bh[n], acc[m][n]);
        asm volatile("s_barrier" ::: "memory");
        const int tmp = b0; b0 = b1; b1 = b2; b2 = tmp;
    }
#undef GSTAGE

    #pragma unroll
    for (int n = 0; n < 2; ++n) {
        const int col  = n0 + wn + n * 16 + fr;
        const float bb = bo[col];
        #pragma unroll
        for (int m = 0; m < 4; ++m)
            #pragma unroll
            for (int r = 0; r < 4; ++r) {
                const int row = m0 + wm + m * 16 + rg + r;
                out[(size_t)row * DIM + col] = acc[m][n][r] + bb;
            }
    }
}

// ---------------------------------------------------------------------------
// Flash attention (R19, FROZEN at ~48.5 us / 4.88e-4): KVBLK=128 staging
// with counted-vmcnt dbuf, 4 waves, QBLK=32/wave, 512 blocks, 80 KB LDS,
// pure-f16 MFMA, exp2-folded scores, lsum via ones-MFMA, XCD swizzle.
// ---------------------------------------------------------------------------
__global__ __launch_bounds__(256, 2) void attn_kernel(
    const f16* __restrict__ QhG, const f16* __restrict__ KhG,
    const f16* __restrict__ VhG, f16* __restrict__ OhG)
{
    __shared__ __align__(16) f16 lds[2][2][8192];   // K: [128][64]; V: [2][64][64]
    __shared__ __align__(16) f16 PL[4][2][1024];    // 16 KB per-wave P^T

    const int tid = threadIdx.x;
    const int l   = tid & 63;
    const int w   = tid >> 6;
    const int fr  = l & 15;
    const int g   = l >> 4;
    const int fk  = g * 8;
    const int rg  = g * 4;
    const int swz = (fr & 7) << 3;

    const int lin  = blockIdx.x + 16 * (blockIdx.y + 16 * blockIdx.z);
    const int sid  = (lin & 7) * 64 + (lin >> 3);
    const int qblk = sid & 15;
    const int head = (sid >> 4) & 15;
    const int batch = sid >> 8;

    const int q0 = qblk * 128;
    const size_t rowbase = (size_t)batch * SEQ;
    const int hcol = head * HD;
    const size_t bhbase = ((size_t)batch * HEADS + head) * (size_t)(SEQ * HD);

    size_t kA[4], vA[4];
    #pragma unroll
    for (int c = 0; c < 4; ++c) {
        const int h0 = (w * 4 + c) * 512 + l * 8;
        kA[c] = bhbase + (size_t)h0;                               // + t*8192
        vA[c] = bhbase + (size_t)((h0 >> 6) & 63) * 2048
              + (size_t)(h0 >> 12) * 64 + (h0 & 63);               // + t*128
    }

#define STAGE(B, T) do {                                                    \
        const size_t _ko = (size_t)(T) * 8192;                              \
        const size_t _vo = (size_t)(T) * 128;                               \
        _Pragma("unroll")                                                   \
        for (int c = 0; c < 4; ++c) {                                       \
            const int lo_ = (w * 4 + c) * 512;                              \
            glds16(KhG + kA[c] + _ko, &lds[B][0][lo_]);                     \
            glds16(VhG + vA[c] + _vo, &lds[B][1][lo_]);                     \
        }                                                                   \
    } while (0)

    STAGE(0, 0);

    f16x8 qh[2][2];
    #pragma unroll
    for (int qb = 0; qb < 2; ++qb) {
        const f16* qp = &QhG[(rowbase + q0 + w * 32 + qb * 16 + fr) * DIM + hcol];
        qh[qb][0] = *reinterpret_cast<const f16x8*>(&qp[fk]);
        qh[qb][1] = *reinterpret_cast<const f16x8*>(&qp[32 + fk]);
    }

    f16x8 onesv;
    #pragma unroll
    for (int i = 0; i < 8; ++i) onesv[i] = (f16)1.0f;

    f32x4 ls[2] = {};
    f32x4 oa[4][2] = {};

    int cur = 0;
    for (int t = 0; t < NT2; ++t) {
        if (t + 1 < NT2) {
            STAGE(cur ^ 1, t + 1);
            asm volatile("s_waitcnt vmcnt(8)\ns_barrier" ::: "memory");
        } else {
            asm volatile("s_waitcnt vmcnt(0)\ns_barrier" ::: "memory");
        }

        #pragma unroll
        for (int hh = 0; hh < 2; ++hh) {
            const f16* Kh = &lds[cur][0][hh * 4096];
            const f16* Vh = &lds[cur][1][hh * 4096];

            f32x4 sa[4][2] = {};
            __builtin_amdgcn_s_setprio(1);
            #pragma unroll
            for (int kvb = 0; kvb < 4; ++kvb) {
                #pragma unroll
                for (int ks = 0; ks < 2; ++ks) {
                    const int o = ((kvb * 16 + fr) * 64 + ks * 32 + fk) ^ swz;
                    const f16x8 kh = *reinterpret_cast<const f16x8*>(&Kh[o]);
                    sa[kvb][0] = MFMA16(kh, qh[0][ks], sa[kvb][0]);
                    sa[kvb][1] = MFMA16(kh, qh[1][ks], sa[kvb][1]);
                }
            }
            __builtin_amdgcn_s_setprio(0);

            f16x8 pf[2][2];
            #pragma unroll
            for (int qb = 0; qb < 2; ++qb) {
                f16* Wh = &PL[w][qb][0];
                #pragma unroll
                for (int kvb = 0; kvb < 4; ++kvb) {
                    const f16x2 p01 = pk_f16(exp2_hw(sa[kvb][qb][0]),
                                             exp2_hw(sa[kvb][qb][1]));
                    const f16x2 p23 = pk_f16(exp2_hw(sa[kvb][qb][2]),
                                             exp2_hw(sa[kvb][qb][3]));
                    f16x4 h4;
                    h4[0] = p01[0]; h4[1] = p01[1]; h4[2] = p23[0]; h4[3] = p23[1];
                    const int po = (fr * 64 + kvb * 16 + rg) ^ swz;
                    *reinterpret_cast<f16x4*>(&Wh[po]) = h4;
                }
                #pragma unroll
                for (int ks = 0; ks < 2; ++ks) {
                    const int ro = (fr * 64 + ks * 32 + fk) ^ swz;
                    pf[qb][ks] = *reinterpret_cast<const f16x8*>(&Wh[ro]);
                }
            }

            __builtin_amdgcn_s_setprio(1);
            #pragma unroll
            for (int qb = 0; qb < 2; ++qb)
                #pragma unroll
                for (int ks = 0; ks < 2; ++ks)
                    ls[qb] = MFMA16(onesv, pf[qb][ks], ls[qb]);
            #pragma unroll
            for (int db = 0; db < 4; ++db) {
                #pragma unroll
                for (int ks = 0; ks < 2; ++ks) {
                    const int vo = (db * 16 + fr) * 64 + ((ks * 32 + fk) ^ swz);
                    const f16x8 vh = *reinterpret_cast<const f16x8*>(&Vh[vo]);
                    oa[db][0] = MFMA16(vh, pf[0][ks], oa[db][0]);
                    oa[db][1] = MFMA16(vh, pf[1][ks], oa[db][1]);
                }
            }
            __builtin_amdgcn_s_setprio(0);
        }
        asm volatile("s_barrier" ::: "memory");
        cur ^= 1;
    }
#undef STAGE

    #pragma unroll
    for (int qb = 0; qb < 2; ++qb) {
        const float inv = 1.0f / ls[qb][0];
        const size_t row = rowbase + q0 + w * 32 + qb * 16 + fr;
        const int s = ((int)row >> 1) & 3;
        #pragma unroll
        for (int db = 0; db < 4; ++db) {
            f16x4 h4;
            #pragma unroll
            for (int j = 0; j < 4; ++j) h4[j] = (f16)(oa[db][qb][j] * inv);
            const int kg = hcol + db * 16 + rg;
            const size_t o = row * DIM + (kg & ~31) + ((kg & 31) ^ (s << 3));
            *reinterpret_cast<f16x4*>(&OhG[o]) = h4;
        }
    }
}

extern "C" void kernel_launch(void* const* d_in, const int* in_sizes, int n_in,
                              void* d_out, int out_size, void* d_ws, size_t ws_size,
                              hipStream_t stream)
{
    const float* x  = (const float*)d_in[0];
    const float* Wq = (const float*)d_in[1];
    const float* bq = (const float*)d_in[2];
    const float* Wk = (const float*)d_in[3];
    const float* bk = (const float*)d_in[4];
    const float* Wv = (const float*)d_in[5];
    const float* bv = (const float*)d_in[6];
    const float* Wo = (const float*)d_in[7];
    const float* bo = (const float*)d_in[8];
    float* out = (float*)d_out;

    const size_t PS = (size_t)MTOT * DIM;   // 4,194,304 elements
    f16* QhG = (f16*)d_ws;                  // 8 MB each
    f16* KhG = QhG + PS;
    f16* VhG = KhG + PS;
    f16* XhG = VhG + PS;                    // reused as Oh after qkv
    f16* WqH = XhG + PS;                    // 2 MB each below
    f16* WkH = WqH + (size_t)DIM * DIM;
    f16* WvH = WkH + (size_t)DIM * DIM;
    f16* WoH = WvH + (size_t)DIM * DIM;
    f16* OhG = XhG;                         // alias: x consumed before attn

    presplit_kernel<<<8192, 256, 0, stream>>>(x, Wq, Wk, Wv, Wo,
                                              XhG, WqH, WkH, WvH, WoH);

    dim3 gqkv(DIM / 64, MTOT / 128);
    qkv_kernel<<<gqkv, 256, 0, stream>>>(XhG, WqH, bq, WkH, bk, WvH, bv,
                                         QhG, KhG, VhG);

    dim3 gattn(SEQ / 128, HEADS, BATCH);
    attn_kernel<<<gattn, 256, 0, stream>>>(QhG, KhG, VhG, OhG);

    dim3 gout(DIM / 64, MTOT / 128);
    oproj_kernel<<<gout, 256, 0, stream>>>(OhG, WoH, bo, out);
}